// Round 1
// baseline (2272.899 us; speedup 1.0000x reference)
//
#include <hip/hip_runtime.h>

#define N_NODES 40000
#define N_EDGES 640000
#define EMB 128
#define NF (N_NODES * EMB)
#define RCP_N (1.0f / (float)N_NODES)
#define BN_EPS 1e-5f

// ---------------------------------------------------------------------------
// Pre-pass: per-node scalar sums over edges
//   s[r]  = sum of edge_attr over out-edges (row)
//   c[r]  = out-degree
//   deg[d]= in-degree (col)
// ---------------------------------------------------------------------------
__global__ __launch_bounds__(256) void edge_scalar_kernel(
    const int* __restrict__ ei, const float* __restrict__ ea,
    float* __restrict__ s, float* __restrict__ c, float* __restrict__ deg)
{
    int idx = blockIdx.x * 256 + threadIdx.x;
    int stride = gridDim.x * 256;
    for (int e = idx; e < N_EDGES; e += stride) {
        int r = ei[e];
        int d = ei[N_EDGES + e];
        atomicAdd(&s[r], ea[e]);
        atomicAdd(&c[r], 1.0f);
        atomicAdd(&deg[d], 1.0f);
    }
}

// Scalar moments of (s, c): out[0..4] = {Σs, Σs², Σc, Σc², Σsc}
__global__ __launch_bounds__(256) void scalar_stats_kernel(
    const float* __restrict__ s, const float* __restrict__ c, float* __restrict__ out)
{
    int idx = blockIdx.x * 256 + threadIdx.x;
    int stride = gridDim.x * 256;
    float a0 = 0.f, a1 = 0.f, a2 = 0.f, a3 = 0.f, a4 = 0.f;
    for (int r = idx; r < N_NODES; r += stride) {
        float sv = s[r], cv = c[r];
        a0 += sv; a1 += sv * sv; a2 += cv; a3 += cv * cv; a4 += sv * cv;
    }
    #pragma unroll
    for (int off = 32; off > 0; off >>= 1) {
        a0 += __shfl_down(a0, off);
        a1 += __shfl_down(a1, off);
        a2 += __shfl_down(a2, off);
        a3 += __shfl_down(a3, off);
        a4 += __shfl_down(a4, off);
    }
    if ((threadIdx.x & 63) == 0) {
        atomicAdd(&out[0], a0);
        atomicAdd(&out[1], a1);
        atomicAdd(&out[2], a2);
        atomicAdd(&out[3], a3);
        atomicAdd(&out[4], a4);
    }
}

// ---------------------------------------------------------------------------
// Initial node MLP pre-activation: Z = node_attr @ W0 + b0  (K=2), + col stats
// ---------------------------------------------------------------------------
__global__ __launch_bounds__(256) void init_node_kernel(
    const float* __restrict__ na, const float* __restrict__ W0,
    const float* __restrict__ b0, float* __restrict__ Z, float* __restrict__ st)
{
    int t = threadIdx.x;
    int col = t & 127, rh = t >> 7;
    float w0 = W0[col], w1 = W0[128 + col], bb = b0[col];
    int rbase = blockIdx.x * 64;
    float sm = 0.f, sq = 0.f;
    #pragma unroll 4
    for (int i = 0; i < 32; ++i) {
        int r = rbase + rh + i * 2;
        float2 nv = *(const float2*)&na[r * 2];
        float v = fmaf(nv.x, w0, fmaf(nv.y, w1, bb));
        Z[r * 128 + col] = v;
        sm += v; sq += v * v;
    }
    __shared__ float red[256];
    red[t] = sm; __syncthreads();
    if (t < 128) atomicAdd(&st[t], red[t] + red[t + 128]);
    __syncthreads();
    red[t] = sq; __syncthreads();
    if (t < 128) atomicAdd(&st[128 + t], red[t] + red[t + 128]);
}

// ---------------------------------------------------------------------------
// Scatter: G[col[e]] += relu(bn(X[row[e]]))   (transform applied on the fly)
// ---------------------------------------------------------------------------
__global__ __launch_bounds__(256) void scatter_kernel(
    const int* __restrict__ ei, const float* __restrict__ X,
    const float* __restrict__ stats_in, const float* __restrict__ g_in,
    const float* __restrict__ bt_in, float* __restrict__ G)
{
    __shared__ float aT[128], bT[128];
    int t = threadIdx.x;
    if (t < 128) {
        float m = stats_in[t] * RCP_N;
        float v = stats_in[128 + t] * RCP_N - m * m;
        float a = g_in[t] * rsqrtf(v + BN_EPS);
        aT[t] = a; bT[t] = bt_in[t] - m * a;
    }
    __syncthreads();
    int lane = t & 63;
    int gw = (blockIdx.x * 256 + t) >> 6;
    int nw = gridDim.x * 4;
    float a0 = aT[2 * lane], b0 = bT[2 * lane];
    float a1 = aT[2 * lane + 1], b1 = bT[2 * lane + 1];
    for (int e = gw; e < N_EDGES; e += nw) {
        int r = ei[e];
        int d = ei[N_EDGES + e];
        float2 v = *(const float2*)&X[r * 128 + 2 * lane];
        float x0 = fmaxf(0.f, fmaf(v.x, a0, b0));
        float x1 = fmaxf(0.f, fmaf(v.y, a1, b1));
        atomicAdd(&G[d * 128 + 2 * lane], x0);
        atomicAdd(&G[d * 128 + 2 * lane + 1], x1);
    }
}

// ---------------------------------------------------------------------------
// GEMM: Out[N,128] = T(Xin)[N,128] @ W[128,128] + bias
//   MODE bit0: input transform relu(a*x+b) from (stats_in, g_in, bt_in)
//   MODE bit1: bias scaled per-row by rowscale[r]
//   MODE bit2: accumulate column sum/sumsq of Out into stats_out
// In-place safe (Xin == Out): each block only reads/writes its own 64 rows,
// and all reads of a chunk complete before the epilogue writes.
// ---------------------------------------------------------------------------
template<int MODE>
__global__ __launch_bounds__(256) void gemm128_kernel(
    const float* Xin, const float* __restrict__ W, const float* __restrict__ bias,
    const float* __restrict__ rowscale,
    const float* __restrict__ stats_in, const float* __restrict__ g_in,
    const float* __restrict__ bt_in,
    float* Out, float* __restrict__ stats_out)
{
    __shared__ float As[64][36];       // +4 pad: kills bank conflicts on column reads
    __shared__ float Bs[32 * 128];
    __shared__ float aT[128], bT[128];
    const int t = threadIdx.x;

    if (MODE & 1) {
        if (t < 128) {
            float m = stats_in[t] * RCP_N;
            float v = stats_in[128 + t] * RCP_N - m * m;
            float a = g_in[t] * rsqrtf(v + BN_EPS);
            aT[t] = a; bT[t] = bt_in[t] - m * a;
        }
        __syncthreads();
    }

    const int row0 = blockIdx.x * 64;
    const int cg = t & 15, rg = t >> 4;
    const int c0 = cg * 8, r0 = rg * 4;

    float acc[4][8];
    #pragma unroll
    for (int i = 0; i < 4; ++i)
        #pragma unroll
        for (int j = 0; j < 8; ++j) acc[i][j] = 0.f;

    for (int kc = 0; kc < 4; ++kc) {
        const int k0 = kc * 32;
        // stage A tile (64x32)
        #pragma unroll
        for (int l = 0; l < 8; ++l) {
            int idx = t + l * 256;
            int r = idx >> 5, k = idx & 31;
            float v = Xin[(row0 + r) * 128 + k0 + k];
            if (MODE & 1) v = fmaxf(0.f, fmaf(v, aT[k0 + k], bT[k0 + k]));
            As[r][k] = v;
        }
        // stage B tile (32x128)
        #pragma unroll
        for (int l = 0; l < 16; ++l) {
            int idx = t + l * 256;
            int k = idx >> 7, n = idx & 127;
            Bs[k * 128 + n] = W[(k0 + k) * 128 + n];
        }
        __syncthreads();
        #pragma unroll
        for (int kk = 0; kk < 32; ++kk) {
            float av[4];
            #pragma unroll
            for (int i = 0; i < 4; ++i) av[i] = As[r0 + i][kk];
            float4 bq0 = *(const float4*)&Bs[kk * 128 + c0];
            float4 bq1 = *(const float4*)&Bs[kk * 128 + c0 + 4];
            float bv[8] = {bq0.x, bq0.y, bq0.z, bq0.w, bq1.x, bq1.y, bq1.z, bq1.w};
            #pragma unroll
            for (int i = 0; i < 4; ++i)
                #pragma unroll
                for (int j = 0; j < 8; ++j)
                    acc[i][j] = fmaf(av[i], bv[j], acc[i][j]);
        }
        __syncthreads();
    }

    // epilogue: bias (+rowscale), write, stats
    float bcol[8];
    #pragma unroll
    for (int j = 0; j < 8; ++j) bcol[j] = bias[c0 + j];

    float fin[4][8];
    #pragma unroll
    for (int i = 0; i < 4; ++i) {
        float rs = (MODE & 2) ? rowscale[row0 + r0 + i] : 1.0f;
        #pragma unroll
        for (int j = 0; j < 8; ++j) fin[i][j] = fmaf(rs, bcol[j], acc[i][j]);
        float4 o0 = {fin[i][0], fin[i][1], fin[i][2], fin[i][3]};
        float4 o1 = {fin[i][4], fin[i][5], fin[i][6], fin[i][7]};
        *(float4*)&Out[(row0 + r0 + i) * 128 + c0] = o0;
        *(float4*)&Out[(row0 + r0 + i) * 128 + c0 + 4] = o1;
    }

    if (MODE & 4) {
        float* red = Bs;   // reuse LDS: 16x128 partials
        __syncthreads();
        #pragma unroll
        for (int j = 0; j < 8; ++j)
            red[rg * 128 + c0 + j] = fin[0][j] + fin[1][j] + fin[2][j] + fin[3][j];
        __syncthreads();
        if (t < 128) {
            float sm = 0.f;
            #pragma unroll
            for (int q = 0; q < 16; ++q) sm += red[q * 128 + t];
            atomicAdd(&stats_out[t], sm);
        }
        __syncthreads();
        #pragma unroll
        for (int j = 0; j < 8; ++j)
            red[rg * 128 + c0 + j] = fin[0][j] * fin[0][j] + fin[1][j] * fin[1][j]
                                   + fin[2][j] * fin[2][j] + fin[3][j] * fin[3][j];
        __syncthreads();
        if (t < 128) {
            float sm = 0.f;
            #pragma unroll
            for (int q = 0; q < 16; ++q) sm += red[q * 128 + t];
            atomicAdd(&stats_out[128 + t], sm);
        }
    }
}

// ---------------------------------------------------------------------------
// Combine: Y = relu( bn(ZN) + bn(AG) + bn_analytic(ea from s,c) )
// ---------------------------------------------------------------------------
__global__ __launch_bounds__(256) void combine_kernel(
    const float* __restrict__ ZN, const float* __restrict__ AG,
    const float* __restrict__ s, const float* __restrict__ c,
    const float* __restrict__ stZN, const float* __restrict__ gn, const float* __restrict__ btn,
    const float* __restrict__ stAG, const float* __restrict__ gnb, const float* __restrict__ btnb,
    const float* __restrict__ scal, const float* __restrict__ We, const float* __restrict__ Be,
    const float* __restrict__ ge, const float* __restrict__ bte,
    float* __restrict__ Y)
{
    __shared__ float A1[128], B1[128], A2[128], B2[128], AE[128], BE[128], CE[128];
    int t = threadIdx.x;
    if (t < 128) {
        float m = stZN[t] * RCP_N;
        float v = stZN[128 + t] * RCP_N - m * m;
        float a = gn[t] * rsqrtf(v + BN_EPS);
        A1[t] = a; B1[t] = btn[t] - m * a;

        m = stAG[t] * RCP_N;
        v = stAG[128 + t] * RCP_N - m * m;
        a = gnb[t] * rsqrtf(v + BN_EPS);
        A2[t] = a; B2[t] = btnb[t] - m * a;

        float ms = scal[0] * RCP_N, vs = scal[1] * RCP_N - ms * ms;
        float mc = scal[2] * RCP_N, vc = scal[3] * RCP_N - mc * mc;
        float cov = scal[4] * RCP_N - ms * mc;
        float we = We[t], be = Be[t];
        float me = ms * we + mc * be;
        float ve = we * we * vs + be * be * vc + 2.f * we * be * cov;
        a = ge[t] * rsqrtf(ve + BN_EPS);
        AE[t] = we * a; BE[t] = be * a; CE[t] = bte[t] - me * a;
    }
    __syncthreads();
    int stride = gridDim.x * 256;
    for (int idx = blockIdx.x * 256 + t; idx < N_NODES * 32; idx += stride) {
        int r = idx >> 5;
        int q = (idx & 31) * 4;
        float4 zn = *(const float4*)&ZN[r * 128 + q];
        float4 ag = *(const float4*)&AG[r * 128 + q];
        float sr = s[r], cr = c[r];
        float4 y;
        y.x = fmaxf(0.f, zn.x * A1[q]     + B1[q]     + ag.x * A2[q]     + B2[q]     + sr * AE[q]     + cr * BE[q]     + CE[q]);
        y.y = fmaxf(0.f, zn.y * A1[q + 1] + B1[q + 1] + ag.y * A2[q + 1] + B2[q + 1] + sr * AE[q + 1] + cr * BE[q + 1] + CE[q + 1]);
        y.z = fmaxf(0.f, zn.z * A1[q + 2] + B1[q + 2] + ag.z * A2[q + 2] + B2[q + 2] + sr * AE[q + 2] + cr * BE[q + 2] + CE[q + 2]);
        y.w = fmaxf(0.f, zn.w * A1[q + 3] + B1[q + 3] + ag.w * A2[q + 3] + B2[q + 3] + sr * AE[q + 3] + cr * BE[q + 3] + CE[q + 3]);
        *(float4*)&Y[r * 128 + q] = y;
    }
}

// Final: Out = relu(bn(Z))
__global__ __launch_bounds__(256) void bnrelu_kernel(
    const float* __restrict__ Z, const float* __restrict__ stz,
    const float* __restrict__ g, const float* __restrict__ bt, float* __restrict__ O)
{
    __shared__ float aT[128], bT[128];
    int t = threadIdx.x;
    if (t < 128) {
        float m = stz[t] * RCP_N;
        float v = stz[128 + t] * RCP_N - m * m;
        float a = g[t] * rsqrtf(v + BN_EPS);
        aT[t] = a; bT[t] = bt[t] - m * a;
    }
    __syncthreads();
    int stride = gridDim.x * 256;
    for (int idx = blockIdx.x * 256 + t; idx < N_NODES * 32; idx += stride) {
        int r = idx >> 5;
        int q = (idx & 31) * 4;
        float4 z = *(const float4*)&Z[r * 128 + q];
        float4 o;
        o.x = fmaxf(0.f, fmaf(z.x, aT[q],     bT[q]));
        o.y = fmaxf(0.f, fmaf(z.y, aT[q + 1], bT[q + 1]));
        o.z = fmaxf(0.f, fmaf(z.z, aT[q + 2], bT[q + 2]));
        o.w = fmaxf(0.f, fmaf(z.w, aT[q + 3], bT[q + 3]));
        *(float4*)&O[r * 128 + q] = o;
    }
}

// ---------------------------------------------------------------------------
extern "C" void kernel_launch(void* const* d_in, const int* in_sizes, int n_in,
                              void* d_out, int out_size, void* d_ws, size_t ws_size,
                              hipStream_t stream)
{
    const float* node_attr = (const float*)d_in[0];
    const int*   ei        = (const int*)d_in[1];
    const float* ea        = (const float*)d_in[2];
    const float* W0    = (const float*)d_in[3];
    const float* b0    = (const float*)d_in[4];
    const float* g0    = (const float*)d_in[5];
    const float* bt0   = (const float*)d_in[6];
    const float* Wnode = (const float*)d_in[7];
    const float* bnode = (const float*)d_in[8];
    const float* Wedge = (const float*)d_in[9];
    const float* bedge = (const float*)d_in[10];
    const float* Wnb   = (const float*)d_in[11];
    const float* bnb   = (const float*)d_in[12];
    const float* gn    = (const float*)d_in[13];
    const float* ge    = (const float*)d_in[14];
    const float* gnb   = (const float*)d_in[15];
    const float* gm1   = (const float*)d_in[16];
    const float* gm2   = (const float*)d_in[17];
    const float* btn   = (const float*)d_in[18];
    const float* bte   = (const float*)d_in[19];
    const float* btnb  = (const float*)d_in[20];
    const float* btm1  = (const float*)d_in[21];
    const float* btm2  = (const float*)d_in[22];
    const float* Wm1   = (const float*)d_in[23];
    const float* bm1   = (const float*)d_in[24];
    const float* Wm2   = (const float*)d_in[25];
    const float* bm2   = (const float*)d_in[26];
    float* out = (float*)d_out;

    // workspace layout (floats): P0 | P1 | ZN(=Z1) | G | s | c | deg | stats
    float* ws = (float*)d_ws;
    float* P0 = ws;
    float* P1 = ws + (size_t)NF;
    float* ZN = ws + 2 * (size_t)NF;
    float* G  = ws + 3 * (size_t)NF;
    float* sN = ws + 4 * (size_t)NF;
    float* cN = sN + N_NODES;
    float* dg = cN + N_NODES;
    float* st = dg + N_NODES;
    // stats layout: [0..255] z0 | [256..263] scalar5 | layer i at 264+i*1024:
    //   zn(+0), aggr(+256), z1(+512), z2(+768)

    hipMemsetAsync(sN, 0, (size_t)(3 * N_NODES + 4096) * sizeof(float), stream);
    edge_scalar_kernel<<<1024, 256, 0, stream>>>(ei, ea, sN, cN, dg);
    scalar_stats_kernel<<<160, 256, 0, stream>>>(sN, cN, st + 256);
    init_node_kernel<<<625, 256, 0, stream>>>(node_attr, W0, b0, P0, st);

    float* X  = P0;
    float* XN = P1;
    const float* xst = st;        // stats of current pre-BN x
    const float* xg  = g0;
    const float* xbt = bt0;

    for (int i = 0; i < 3; ++i) {
        float* lay = st + 264 + i * 1024;
        hipMemsetAsync(G, 0, (size_t)NF * sizeof(float), stream);
        // neighbor aggregation of transformed x rows (raw sums)
        scatter_kernel<<<2048, 256, 0, stream>>>(ei, X, xst, xg, xbt, G);
        // node branch: ZN = relu(bn(X)) @ Wnode + bnode   (+stats)
        gemm128_kernel<5><<<625, 256, 0, stream>>>(
            X, Wnode + i * 16384, bnode + i * 128, nullptr, xst, xg, xbt, ZN, lay);
        // neighbor branch GEMM (in-place): G = G @ Wnb + deg*bnb   (+stats)
        gemm128_kernel<6><<<625, 256, 0, stream>>>(
            G, Wnb + i * 16384, bnb + i * 128, dg, nullptr, nullptr, nullptr, G, lay + 256);
        // y = relu(bn(ZN) + bn(G) + ea)  -> d_out (used as y buffer)
        combine_kernel<<<2048, 256, 0, stream>>>(
            ZN, G, sN, cN,
            lay, gn + i * 128, btn + i * 128,
            lay + 256, gnb + i * 128, btnb + i * 128,
            st + 256, Wedge + i * 128, bedge + i * 128, ge + i * 128, bte + i * 128,
            out);
        // z1 = y @ Wm1 + bm1   (+stats), overwrites ZN
        gemm128_kernel<4><<<625, 256, 0, stream>>>(
            out, Wm1 + i * 16384, bm1 + i * 128, nullptr, nullptr, nullptr, nullptr, ZN, lay + 512);
        // z2 = relu(bn(z1)) @ Wm2 + bm2   (+stats) -> XN
        gemm128_kernel<5><<<625, 256, 0, stream>>>(
            ZN, Wm2 + i * 16384, bm2 + i * 128, nullptr, lay + 512, gm1 + i * 128, btm1 + i * 128, XN, lay + 768);

        float* tmp = X; X = XN; XN = tmp;
        xst = lay + 768;
        xg  = gm2 + i * 128;
        xbt = btm2 + i * 128;
    }
    // final activation
    bnrelu_kernel<<<2048, 256, 0, stream>>>(X, xst, xg, xbt, out);
}

// Round 2
// 963.204 us; speedup vs baseline: 2.3597x; 2.3597x over previous
//
#include <hip/hip_runtime.h>

#define N_NODES 40000
#define N_EDGES 640000
#define EMB 128
#define NF (N_NODES * EMB)
#define RCP_N (1.0f / (float)N_NODES)
#define BN_EPS 1e-5f

// ---------------------------------------------------------------------------
// Pre-pass: per-node scalar sums over edges
//   s[r]  = sum of edge_attr over out-edges (row)
//   c[r]  = out-degree
//   deg[d]= in-degree (col)
// ---------------------------------------------------------------------------
__global__ __launch_bounds__(256) void edge_scalar_kernel(
    const int* __restrict__ ei, const float* __restrict__ ea,
    float* __restrict__ s, float* __restrict__ c, float* __restrict__ deg)
{
    int idx = blockIdx.x * 256 + threadIdx.x;
    int stride = gridDim.x * 256;
    for (int e = idx; e < N_EDGES; e += stride) {
        int r = ei[e];
        int d = ei[N_EDGES + e];
        atomicAdd(&s[r], ea[e]);
        atomicAdd(&c[r], 1.0f);
        atomicAdd(&deg[d], 1.0f);
    }
}

// Scalar moments of (s, c): out[0..4] = {Σs, Σs², Σc, Σc², Σsc}
__global__ __launch_bounds__(256) void scalar_stats_kernel(
    const float* __restrict__ s, const float* __restrict__ c, float* __restrict__ out)
{
    int idx = blockIdx.x * 256 + threadIdx.x;
    int stride = gridDim.x * 256;
    float a0 = 0.f, a1 = 0.f, a2 = 0.f, a3 = 0.f, a4 = 0.f;
    for (int r = idx; r < N_NODES; r += stride) {
        float sv = s[r], cv = c[r];
        a0 += sv; a1 += sv * sv; a2 += cv; a3 += cv * cv; a4 += sv * cv;
    }
    #pragma unroll
    for (int off = 32; off > 0; off >>= 1) {
        a0 += __shfl_down(a0, off);
        a1 += __shfl_down(a1, off);
        a2 += __shfl_down(a2, off);
        a3 += __shfl_down(a3, off);
        a4 += __shfl_down(a4, off);
    }
    if ((threadIdx.x & 63) == 0) {
        atomicAdd(&out[0], a0);
        atomicAdd(&out[1], a1);
        atomicAdd(&out[2], a2);
        atomicAdd(&out[3], a3);
        atomicAdd(&out[4], a4);
    }
}

// ---------------------------------------------------------------------------
// CSR build: exclusive scan of in-degrees (single block), then bucket fill.
// ---------------------------------------------------------------------------
__global__ __launch_bounds__(256) void scan_kernel(
    const float* __restrict__ deg, int* __restrict__ start)
{
    __shared__ int partials[256];
    int t = threadIdx.x;
    const int CHUNK = (N_NODES + 255) / 256;   // 157
    int b0 = t * CHUNK;
    int b1 = min(b0 + CHUNK, N_NODES);
    int lsum = 0;
    for (int i = b0; i < b1; ++i) lsum += (int)deg[i];
    partials[t] = lsum;
    __syncthreads();
    for (int off = 1; off < 256; off <<= 1) {
        int v = (t >= off) ? partials[t - off] : 0;
        __syncthreads();
        partials[t] += v;
        __syncthreads();
    }
    int prefix = (t == 0) ? 0 : partials[t - 1];  // exclusive
    for (int i = b0; i < b1; ++i) {
        start[i] = prefix;
        prefix += (int)deg[i];
    }
    if (t == 255) start[N_NODES] = prefix;
}

__global__ __launch_bounds__(256) void bucket_kernel(
    const int* __restrict__ ei, const int* __restrict__ start,
    int* __restrict__ cursor, int* __restrict__ csr)
{
    int idx = blockIdx.x * 256 + threadIdx.x;
    int stride = gridDim.x * 256;
    for (int e = idx; e < N_EDGES; e += stride) {
        int r = ei[e];
        int d = ei[N_EDGES + e];
        int pos = atomicAdd(&cursor[d], 1);
        csr[start[d] + pos] = r;
    }
}

// ---------------------------------------------------------------------------
// Gather: G[d] = sum over in-edges of XT[src]   (one wave per node, float2/lane)
// ---------------------------------------------------------------------------
__global__ __launch_bounds__(256) void gather_kernel(
    const int* __restrict__ start, const int* __restrict__ csr,
    const float* __restrict__ XT, float* __restrict__ G)
{
    int wid = (blockIdx.x * 256 + threadIdx.x) >> 6;
    int lane = threadIdx.x & 63;
    if (wid >= N_NODES) return;
    int e0 = start[wid], e1 = start[wid + 1];
    float a0 = 0.f, a1 = 0.f, a2 = 0.f, a3 = 0.f;
    int e = e0;
    for (; e + 1 < e1; e += 2) {
        int r0 = csr[e], r1 = csr[e + 1];
        float2 v0 = *(const float2*)&XT[(size_t)r0 * 128 + 2 * lane];
        float2 v1 = *(const float2*)&XT[(size_t)r1 * 128 + 2 * lane];
        a0 += v0.x; a1 += v0.y; a2 += v1.x; a3 += v1.y;
    }
    if (e < e1) {
        int r0 = csr[e];
        float2 v0 = *(const float2*)&XT[(size_t)r0 * 128 + 2 * lane];
        a0 += v0.x; a1 += v0.y;
    }
    float2 o = {a0 + a2, a1 + a3};
    *(float2*)&G[(size_t)wid * 128 + 2 * lane] = o;
}

// ---------------------------------------------------------------------------
// Initial node MLP pre-activation: Z = node_attr @ W0 + b0  (K=2), + col stats
// ---------------------------------------------------------------------------
__global__ __launch_bounds__(256) void init_node_kernel(
    const float* __restrict__ na, const float* __restrict__ W0,
    const float* __restrict__ b0, float* __restrict__ Z, float* __restrict__ st)
{
    int t = threadIdx.x;
    int col = t & 127, rh = t >> 7;
    float w0 = W0[col], w1 = W0[128 + col], bb = b0[col];
    int rbase = blockIdx.x * 64;
    float sm = 0.f, sq = 0.f;
    #pragma unroll 4
    for (int i = 0; i < 32; ++i) {
        int r = rbase + rh + i * 2;
        float2 nv = *(const float2*)&na[r * 2];
        float v = fmaf(nv.x, w0, fmaf(nv.y, w1, bb));
        Z[r * 128 + col] = v;
        sm += v; sq += v * v;
    }
    __shared__ float red[256];
    red[t] = sm; __syncthreads();
    if (t < 128) atomicAdd(&st[t], red[t] + red[t + 128]);
    __syncthreads();
    red[t] = sq; __syncthreads();
    if (t < 128) atomicAdd(&st[128 + t], red[t] + red[t + 128]);
}

// ---------------------------------------------------------------------------
// GEMM: Out[N,128] = T(Xin)[N,128] @ W[128,128] + bias
//   MODE bit0: input transform relu(a*x+b) from (stats_in, g_in, bt_in)
//   MODE bit1: bias scaled per-row by rowscale[r]
//   MODE bit2: accumulate column sum/sumsq of Out into stats_out
// ---------------------------------------------------------------------------
template<int MODE>
__global__ __launch_bounds__(256) void gemm128_kernel(
    const float* Xin, const float* __restrict__ W, const float* __restrict__ bias,
    const float* __restrict__ rowscale,
    const float* __restrict__ stats_in, const float* __restrict__ g_in,
    const float* __restrict__ bt_in,
    float* Out, float* __restrict__ stats_out)
{
    __shared__ float As[64][36];
    __shared__ float Bs[32 * 128];
    __shared__ float aT[128], bT[128];
    const int t = threadIdx.x;

    if (MODE & 1) {
        if (t < 128) {
            float m = stats_in[t] * RCP_N;
            float v = stats_in[128 + t] * RCP_N - m * m;
            float a = g_in[t] * rsqrtf(v + BN_EPS);
            aT[t] = a; bT[t] = bt_in[t] - m * a;
        }
        __syncthreads();
    }

    const int row0 = blockIdx.x * 64;
    const int cg = t & 15, rg = t >> 4;
    const int c0 = cg * 8, r0 = rg * 4;

    float acc[4][8];
    #pragma unroll
    for (int i = 0; i < 4; ++i)
        #pragma unroll
        for (int j = 0; j < 8; ++j) acc[i][j] = 0.f;

    for (int kc = 0; kc < 4; ++kc) {
        const int k0 = kc * 32;
        #pragma unroll
        for (int l = 0; l < 8; ++l) {
            int idx = t + l * 256;
            int r = idx >> 5, k = idx & 31;
            float v = Xin[(row0 + r) * 128 + k0 + k];
            if (MODE & 1) v = fmaxf(0.f, fmaf(v, aT[k0 + k], bT[k0 + k]));
            As[r][k] = v;
        }
        #pragma unroll
        for (int l = 0; l < 16; ++l) {
            int idx = t + l * 256;
            int k = idx >> 7, n = idx & 127;
            Bs[k * 128 + n] = W[(k0 + k) * 128 + n];
        }
        __syncthreads();
        #pragma unroll
        for (int kk = 0; kk < 32; ++kk) {
            float av[4];
            #pragma unroll
            for (int i = 0; i < 4; ++i) av[i] = As[r0 + i][kk];
            float4 bq0 = *(const float4*)&Bs[kk * 128 + c0];
            float4 bq1 = *(const float4*)&Bs[kk * 128 + c0 + 4];
            float bv[8] = {bq0.x, bq0.y, bq0.z, bq0.w, bq1.x, bq1.y, bq1.z, bq1.w};
            #pragma unroll
            for (int i = 0; i < 4; ++i)
                #pragma unroll
                for (int j = 0; j < 8; ++j)
                    acc[i][j] = fmaf(av[i], bv[j], acc[i][j]);
        }
        __syncthreads();
    }

    float bcol[8];
    #pragma unroll
    for (int j = 0; j < 8; ++j) bcol[j] = bias[c0 + j];

    float fin[4][8];
    #pragma unroll
    for (int i = 0; i < 4; ++i) {
        float rs = (MODE & 2) ? rowscale[row0 + r0 + i] : 1.0f;
        #pragma unroll
        for (int j = 0; j < 8; ++j) fin[i][j] = fmaf(rs, bcol[j], acc[i][j]);
        float4 o0 = {fin[i][0], fin[i][1], fin[i][2], fin[i][3]};
        float4 o1 = {fin[i][4], fin[i][5], fin[i][6], fin[i][7]};
        *(float4*)&Out[(row0 + r0 + i) * 128 + c0] = o0;
        *(float4*)&Out[(row0 + r0 + i) * 128 + c0 + 4] = o1;
    }

    if (MODE & 4) {
        float* red = Bs;
        __syncthreads();
        #pragma unroll
        for (int j = 0; j < 8; ++j)
            red[rg * 128 + c0 + j] = fin[0][j] + fin[1][j] + fin[2][j] + fin[3][j];
        __syncthreads();
        if (t < 128) {
            float sm = 0.f;
            #pragma unroll
            for (int q = 0; q < 16; ++q) sm += red[q * 128 + t];
            atomicAdd(&stats_out[t], sm);
        }
        __syncthreads();
        #pragma unroll
        for (int j = 0; j < 8; ++j)
            red[rg * 128 + c0 + j] = fin[0][j] * fin[0][j] + fin[1][j] * fin[1][j]
                                   + fin[2][j] * fin[2][j] + fin[3][j] * fin[3][j];
        __syncthreads();
        if (t < 128) {
            float sm = 0.f;
            #pragma unroll
            for (int q = 0; q < 16; ++q) sm += red[q * 128 + t];
            atomicAdd(&stats_out[128 + t], sm);
        }
    }
}

// ---------------------------------------------------------------------------
// Combine: Y = relu( bn(ZN) + bn(AG) + bn_analytic(ea from s,c) )
// ---------------------------------------------------------------------------
__global__ __launch_bounds__(256) void combine_kernel(
    const float* __restrict__ ZN, const float* __restrict__ AG,
    const float* __restrict__ s, const float* __restrict__ c,
    const float* __restrict__ stZN, const float* __restrict__ gn, const float* __restrict__ btn,
    const float* __restrict__ stAG, const float* __restrict__ gnb, const float* __restrict__ btnb,
    const float* __restrict__ scal, const float* __restrict__ We, const float* __restrict__ Be,
    const float* __restrict__ ge, const float* __restrict__ bte,
    float* __restrict__ Y)
{
    __shared__ float A1[128], B1[128], A2[128], B2[128], AE[128], BE[128], CE[128];
    int t = threadIdx.x;
    if (t < 128) {
        float m = stZN[t] * RCP_N;
        float v = stZN[128 + t] * RCP_N - m * m;
        float a = gn[t] * rsqrtf(v + BN_EPS);
        A1[t] = a; B1[t] = btn[t] - m * a;

        m = stAG[t] * RCP_N;
        v = stAG[128 + t] * RCP_N - m * m;
        a = gnb[t] * rsqrtf(v + BN_EPS);
        A2[t] = a; B2[t] = btnb[t] - m * a;

        float ms = scal[0] * RCP_N, vs = scal[1] * RCP_N - ms * ms;
        float mc = scal[2] * RCP_N, vc = scal[3] * RCP_N - mc * mc;
        float cov = scal[4] * RCP_N - ms * mc;
        float we = We[t], be = Be[t];
        float me = ms * we + mc * be;
        float ve = we * we * vs + be * be * vc + 2.f * we * be * cov;
        a = ge[t] * rsqrtf(ve + BN_EPS);
        AE[t] = we * a; BE[t] = be * a; CE[t] = bte[t] - me * a;
    }
    __syncthreads();
    int stride = gridDim.x * 256;
    for (int idx = blockIdx.x * 256 + t; idx < N_NODES * 32; idx += stride) {
        int r = idx >> 5;
        int q = (idx & 31) * 4;
        float4 zn = *(const float4*)&ZN[r * 128 + q];
        float4 ag = *(const float4*)&AG[r * 128 + q];
        float sr = s[r], cr = c[r];
        float4 y;
        y.x = fmaxf(0.f, zn.x * A1[q]     + B1[q]     + ag.x * A2[q]     + B2[q]     + sr * AE[q]     + cr * BE[q]     + CE[q]);
        y.y = fmaxf(0.f, zn.y * A1[q + 1] + B1[q + 1] + ag.y * A2[q + 1] + B2[q + 1] + sr * AE[q + 1] + cr * BE[q + 1] + CE[q + 1]);
        y.z = fmaxf(0.f, zn.z * A1[q + 2] + B1[q + 2] + ag.z * A2[q + 2] + B2[q + 2] + sr * AE[q + 2] + cr * BE[q + 2] + CE[q + 2]);
        y.w = fmaxf(0.f, zn.w * A1[q + 3] + B1[q + 3] + ag.w * A2[q + 3] + B2[q + 3] + sr * AE[q + 3] + cr * BE[q + 3] + CE[q + 3]);
        *(float4*)&Y[r * 128 + q] = y;
    }
}

// Elementwise: O = relu(bn(Z)); in-place safe (O may equal Z)
__global__ __launch_bounds__(256) void bnrelu_kernel(
    const float* __restrict__ Z, const float* __restrict__ stz,
    const float* __restrict__ g, const float* __restrict__ bt, float* __restrict__ O)
{
    __shared__ float aT[128], bT[128];
    int t = threadIdx.x;
    if (t < 128) {
        float m = stz[t] * RCP_N;
        float v = stz[128 + t] * RCP_N - m * m;
        float a = g[t] * rsqrtf(v + BN_EPS);
        aT[t] = a; bT[t] = bt[t] - m * a;
    }
    __syncthreads();
    int stride = gridDim.x * 256;
    for (int idx = blockIdx.x * 256 + t; idx < N_NODES * 32; idx += stride) {
        int r = idx >> 5;
        int q = (idx & 31) * 4;
        float4 z = *(const float4*)&Z[r * 128 + q];
        float4 o;
        o.x = fmaxf(0.f, fmaf(z.x, aT[q],     bT[q]));
        o.y = fmaxf(0.f, fmaf(z.y, aT[q + 1], bT[q + 1]));
        o.z = fmaxf(0.f, fmaf(z.z, aT[q + 2], bT[q + 2]));
        o.w = fmaxf(0.f, fmaf(z.w, aT[q + 3], bT[q + 3]));
        *(float4*)&O[r * 128 + q] = o;
    }
}

// ---------------------------------------------------------------------------
extern "C" void kernel_launch(void* const* d_in, const int* in_sizes, int n_in,
                              void* d_out, int out_size, void* d_ws, size_t ws_size,
                              hipStream_t stream)
{
    const float* node_attr = (const float*)d_in[0];
    const int*   ei        = (const int*)d_in[1];
    const float* ea        = (const float*)d_in[2];
    const float* W0    = (const float*)d_in[3];
    const float* b0    = (const float*)d_in[4];
    const float* g0    = (const float*)d_in[5];
    const float* bt0   = (const float*)d_in[6];
    const float* Wnode = (const float*)d_in[7];
    const float* bnode = (const float*)d_in[8];
    const float* Wedge = (const float*)d_in[9];
    const float* bedge = (const float*)d_in[10];
    const float* Wnb   = (const float*)d_in[11];
    const float* bnb   = (const float*)d_in[12];
    const float* gn    = (const float*)d_in[13];
    const float* ge    = (const float*)d_in[14];
    const float* gnb   = (const float*)d_in[15];
    const float* gm1   = (const float*)d_in[16];
    const float* gm2   = (const float*)d_in[17];
    const float* btn   = (const float*)d_in[18];
    const float* bte   = (const float*)d_in[19];
    const float* btnb  = (const float*)d_in[20];
    const float* btm1  = (const float*)d_in[21];
    const float* btm2  = (const float*)d_in[22];
    const float* Wm1   = (const float*)d_in[23];
    const float* bm1   = (const float*)d_in[24];
    const float* Wm2   = (const float*)d_in[25];
    const float* bm2   = (const float*)d_in[26];
    float* out = (float*)d_out;

    // workspace: P0 | P1 | ZN | G | sN | cN | dg | st(4096) | start | cursor | csr
    float* ws = (float*)d_ws;
    float* P0 = ws;
    float* P1 = ws + (size_t)NF;
    float* ZN = ws + 2 * (size_t)NF;
    float* G  = ws + 3 * (size_t)NF;
    float* sN = ws + 4 * (size_t)NF;
    float* cN = sN + N_NODES;
    float* dg = cN + N_NODES;
    float* st = dg + N_NODES;
    int* startA = (int*)(st + 4096);
    int* cursor = startA + (N_NODES + 1);
    int* csr    = cursor + N_NODES;
    // stats layout: [0..255] z0 | [256..263] scalar5 | layer i at 264+i*1024

    // zero: sN, cN, dg, st, start(no need but cheap), cursor
    hipMemsetAsync(sN, 0, (size_t)(5 * N_NODES + 4097) * sizeof(float), stream);
    edge_scalar_kernel<<<1024, 256, 0, stream>>>(ei, ea, sN, cN, dg);
    scalar_stats_kernel<<<160, 256, 0, stream>>>(sN, cN, st + 256);
    scan_kernel<<<1, 256, 0, stream>>>(dg, startA);
    bucket_kernel<<<1024, 256, 0, stream>>>(ei, startA, cursor, csr);
    init_node_kernel<<<625, 256, 0, stream>>>(node_attr, W0, b0, P0, st);

    float* X  = P0;
    float* XN = P1;
    const float* xst = st;
    const float* xg  = g0;
    const float* xbt = bt0;

    for (int i = 0; i < 3; ++i) {
        float* lay = st + 264 + i * 1024;
        // X <- relu(bn(X)) in place
        bnrelu_kernel<<<2048, 256, 0, stream>>>(X, xst, xg, xbt, X);
        // neighbor aggregation (raw sums) via CSR gather
        gather_kernel<<<10000, 256, 0, stream>>>(startA, csr, X, G);
        // node branch: ZN = X @ Wnode + bnode   (+stats)
        gemm128_kernel<4><<<625, 256, 0, stream>>>(
            X, Wnode + i * 16384, bnode + i * 128, nullptr, nullptr, nullptr, nullptr, ZN, lay);
        // neighbor branch GEMM (in-place): G = G @ Wnb + deg*bnb   (+stats)
        gemm128_kernel<6><<<625, 256, 0, stream>>>(
            G, Wnb + i * 16384, bnb + i * 128, dg, nullptr, nullptr, nullptr, G, lay + 256);
        // y = relu(bn(ZN) + bn(G) + ea)  -> d_out
        combine_kernel<<<2048, 256, 0, stream>>>(
            ZN, G, sN, cN,
            lay, gn + i * 128, btn + i * 128,
            lay + 256, gnb + i * 128, btnb + i * 128,
            st + 256, Wedge + i * 128, bedge + i * 128, ge + i * 128, bte + i * 128,
            out);
        // z1 = y @ Wm1 + bm1   (+stats)
        gemm128_kernel<4><<<625, 256, 0, stream>>>(
            out, Wm1 + i * 16384, bm1 + i * 128, nullptr, nullptr, nullptr, nullptr, ZN, lay + 512);
        // z2 = relu(bn(z1)) @ Wm2 + bm2   (+stats) -> XN
        gemm128_kernel<5><<<625, 256, 0, stream>>>(
            ZN, Wm2 + i * 16384, bm2 + i * 128, nullptr, lay + 512, gm1 + i * 128, btm1 + i * 128, XN, lay + 768);

        float* tmp = X; X = XN; XN = tmp;
        xst = lay + 768;
        xg  = gm2 + i * 128;
        xbt = btm2 + i * 128;
    }
    bnrelu_kernel<<<2048, 256, 0, stream>>>(X, xst, xg, xbt, out);
}

// Round 3
// 780.382 us; speedup vs baseline: 2.9125x; 1.2343x over previous
//
#include <hip/hip_runtime.h>

#define N_NODES 40000
#define N_EDGES 640000
#define EMB 128
#define NF ((size_t)N_NODES * EMB)
#define RCP_N (1.0f / (float)N_NODES)
#define BN_EPS 1e-5f

typedef __bf16 bf16x8v __attribute__((ext_vector_type(8)));
typedef float f32x4v __attribute__((ext_vector_type(4)));
typedef unsigned short ushort8v __attribute__((ext_vector_type(8)));

__device__ __forceinline__ unsigned short f2b(float v) {
    return __builtin_bit_cast(unsigned short, (__bf16)v);
}
__device__ __forceinline__ float blo2f(unsigned u) {
    return __builtin_bit_cast(float, u << 16);
}
__device__ __forceinline__ float bhi2f(unsigned u) {
    return __builtin_bit_cast(float, u & 0xffff0000u);
}

// ---------------------------------------------------------------------------
// Pre-pass: per-node scalar sums over edges
// ---------------------------------------------------------------------------
__global__ __launch_bounds__(256) void edge_scalar_kernel(
    const int* __restrict__ ei, const float* __restrict__ ea,
    float* __restrict__ s, float* __restrict__ c, float* __restrict__ deg)
{
    int idx = blockIdx.x * 256 + threadIdx.x;
    int stride = gridDim.x * 256;
    for (int e = idx; e < N_EDGES; e += stride) {
        int r = ei[e];
        int d = ei[N_EDGES + e];
        atomicAdd(&s[r], ea[e]);
        atomicAdd(&c[r], 1.0f);
        atomicAdd(&deg[d], 1.0f);
    }
}

// Scalar moments of (s, c): out[0..4] = {Σs, Σs², Σc, Σc², Σsc}
__global__ __launch_bounds__(256) void scalar_stats_kernel(
    const float* __restrict__ s, const float* __restrict__ c, float* __restrict__ out)
{
    int idx = blockIdx.x * 256 + threadIdx.x;
    int stride = gridDim.x * 256;
    float a0 = 0.f, a1 = 0.f, a2 = 0.f, a3 = 0.f, a4 = 0.f;
    for (int r = idx; r < N_NODES; r += stride) {
        float sv = s[r], cv = c[r];
        a0 += sv; a1 += sv * sv; a2 += cv; a3 += cv * cv; a4 += sv * cv;
    }
    #pragma unroll
    for (int off = 32; off > 0; off >>= 1) {
        a0 += __shfl_down(a0, off);
        a1 += __shfl_down(a1, off);
        a2 += __shfl_down(a2, off);
        a3 += __shfl_down(a3, off);
        a4 += __shfl_down(a4, off);
    }
    if ((threadIdx.x & 63) == 0) {
        atomicAdd(&out[0], a0);
        atomicAdd(&out[1], a1);
        atomicAdd(&out[2], a2);
        atomicAdd(&out[3], a3);
        atomicAdd(&out[4], a4);
    }
}

// ---------------------------------------------------------------------------
// CSR build
// ---------------------------------------------------------------------------
__global__ __launch_bounds__(256) void scan_kernel(
    const float* __restrict__ deg, int* __restrict__ start)
{
    __shared__ int partials[256];
    int t = threadIdx.x;
    const int CHUNK = (N_NODES + 255) / 256;
    int b0 = t * CHUNK;
    int b1 = min(b0 + CHUNK, N_NODES);
    int lsum = 0;
    for (int i = b0; i < b1; ++i) lsum += (int)deg[i];
    partials[t] = lsum;
    __syncthreads();
    for (int off = 1; off < 256; off <<= 1) {
        int v = (t >= off) ? partials[t - off] : 0;
        __syncthreads();
        partials[t] += v;
        __syncthreads();
    }
    int prefix = (t == 0) ? 0 : partials[t - 1];
    for (int i = b0; i < b1; ++i) {
        start[i] = prefix;
        prefix += (int)deg[i];
    }
    if (t == 255) start[N_NODES] = prefix;
}

__global__ __launch_bounds__(256) void bucket_kernel(
    const int* __restrict__ ei, const int* __restrict__ start,
    int* __restrict__ cursor, int* __restrict__ csr)
{
    int idx = blockIdx.x * 256 + threadIdx.x;
    int stride = gridDim.x * 256;
    for (int e = idx; e < N_EDGES; e += stride) {
        int r = ei[e];
        int d = ei[N_EDGES + e];
        int pos = atomicAdd(&cursor[d], 1);
        csr[start[d] + pos] = r;
    }
}

// ---------------------------------------------------------------------------
// Gather: G[d] = sum over in-edges of Xb[src] (bf16 in, f32 out); 1 wave/node
// ---------------------------------------------------------------------------
__global__ __launch_bounds__(256) void gather_kernel(
    const int* __restrict__ start, const int* __restrict__ csr,
    const unsigned short* __restrict__ Xb, float* __restrict__ G)
{
    int wid = (blockIdx.x * 256 + threadIdx.x) >> 6;
    int lane = threadIdx.x & 63;
    if (wid >= N_NODES) return;
    int e0 = start[wid], e1 = start[wid + 1];
    float a0 = 0.f, a1 = 0.f, a2 = 0.f, a3 = 0.f;
    int e = e0;
    for (; e + 1 < e1; e += 2) {
        int r0 = csr[e], r1 = csr[e + 1];
        unsigned v0 = *(const unsigned*)&Xb[(size_t)r0 * 128 + 2 * lane];
        unsigned v1 = *(const unsigned*)&Xb[(size_t)r1 * 128 + 2 * lane];
        a0 += blo2f(v0); a1 += bhi2f(v0);
        a2 += blo2f(v1); a3 += bhi2f(v1);
    }
    if (e < e1) {
        unsigned v0 = *(const unsigned*)&Xb[(size_t)csr[e] * 128 + 2 * lane];
        a0 += blo2f(v0); a1 += bhi2f(v0);
    }
    float2 o = {a0 + a2, a1 + a3};
    *(float2*)&G[(size_t)wid * 128 + 2 * lane] = o;
}

// ---------------------------------------------------------------------------
// Initial node MLP pre-activation: Z = node_attr @ W0 + b0 (K=2), + col stats
// ---------------------------------------------------------------------------
__global__ __launch_bounds__(256) void init_node_kernel(
    const float* __restrict__ na, const float* __restrict__ W0,
    const float* __restrict__ b0, float* __restrict__ Z, float* __restrict__ st)
{
    int t = threadIdx.x;
    int col = t & 127, rh = t >> 7;
    float w0 = W0[col], w1 = W0[128 + col], bb = b0[col];
    int rbase = blockIdx.x * 64;
    float sm = 0.f, sq = 0.f;
    #pragma unroll 4
    for (int i = 0; i < 32; ++i) {
        int r = rbase + rh + i * 2;
        float2 nv = *(const float2*)&na[r * 2];
        float v = fmaf(nv.x, w0, fmaf(nv.y, w1, bb));
        Z[(size_t)r * 128 + col] = v;
        sm += v; sq += v * v;
    }
    __shared__ float red[256];
    red[t] = sm; __syncthreads();
    if (t < 128) atomicAdd(&st[t], red[t] + red[t + 128]);
    __syncthreads();
    red[t] = sq; __syncthreads();
    if (t < 128) atomicAdd(&st[128 + t], red[t] + red[t + 128]);
}

// ---------------------------------------------------------------------------
// Weight prep: Wt[mat][n][k] = bf16(W[mat][k][n]), 12 matrices of 128x128.
// grid = 48 blocks (12 matrices x 4 k-chunks of 32)
// ---------------------------------------------------------------------------
__global__ __launch_bounds__(256) void wprep_kernel(
    const float* __restrict__ Wnode, const float* __restrict__ Wnb,
    const float* __restrict__ Wm1, const float* __restrict__ Wm2,
    unsigned short* __restrict__ Wt)
{
    __shared__ float tile[32][129];
    int b = blockIdx.x;
    int mat = b >> 2, kc = (b & 3) * 32;
    int grp = mat / 3, lay = mat % 3;
    const float* src = (grp == 0) ? Wnode : (grp == 1) ? Wnb : (grp == 2) ? Wm1 : Wm2;
    src += (size_t)lay * 16384;
    int t = threadIdx.x;
    #pragma unroll
    for (int i = 0; i < 16; ++i) {
        int idx = t + i * 256;
        int r = idx >> 7, n = idx & 127;
        tile[r][n] = src[(size_t)(kc + r) * 128 + n];
    }
    __syncthreads();
    int n = t >> 1, h = (t & 1) * 16;
    ushort8v o0, o1;
    #pragma unroll
    for (int j = 0; j < 8; ++j) o0[j] = f2b(tile[h + j][n]);
    #pragma unroll
    for (int j = 0; j < 8; ++j) o1[j] = f2b(tile[h + 8 + j][n]);
    unsigned short* dst = &Wt[(size_t)mat * 16384 + n * 128 + kc + h];
    *(ushort8v*)dst = o0;
    *(ushort8v*)(dst + 8) = o1;
}

// ---------------------------------------------------------------------------
// MFMA GEMM: Out[N,128] = T(A)[N,128] @ W[128,128] + bias, + column stats.
//   AF32: A is f32 (else bf16);  TRANS: relu(a*x+b) on A;  RSC: bias*rowscale
// 64-row tiles (grid 625), 256 threads = 4 waves, wave = 16 rows x 128 cols.
// ---------------------------------------------------------------------------
template<bool AF32, bool TRANS, bool RSC>
__global__ __launch_bounds__(256) void mfma_gemm_kernel(
    const void* __restrict__ Ain, const unsigned short* __restrict__ Wt,
    const float* __restrict__ bias, const float* __restrict__ rowscale,
    const float* __restrict__ stats_in, const float* __restrict__ g_in,
    const float* __restrict__ bt_in,
    float* __restrict__ Out, float* __restrict__ stats_out)
{
    __shared__ __align__(16) unsigned short As[64 * 128];   // swizzled bf16
    __shared__ __align__(16) unsigned short Bs[128 * 128];  // swizzled bf16 W^T
    __shared__ float aT[128], bT[128];
    __shared__ float redS[4][128], redQ[4][128];

    const int t = threadIdx.x;
    const int row0 = blockIdx.x * 64;

    if (TRANS) {
        if (t < 128) {
            float m = stats_in[t] * RCP_N;
            float v = stats_in[128 + t] * RCP_N - m * m;
            float a = g_in[t] * rsqrtf(v + BN_EPS);
            aT[t] = a; bT[t] = bt_in[t] - m * a;
        }
        __syncthreads();
    }

    // ---- stage B (W^T bf16, 128x128) with XOR swizzle
    #pragma unroll
    for (int i = 0; i < 8; ++i) {
        int cch = t + i * 256;
        int n = cch >> 4, off = (cch & 15) << 3;
        ushort8v w = *(const ushort8v*)&Wt[n * 128 + off];
        *(ushort8v*)&Bs[(n * 128 + off) ^ ((n & 7) << 3)] = w;
    }
    // ---- stage A (64x128 -> bf16) with XOR swizzle
    if (!AF32) {
        const unsigned short* Xu = (const unsigned short*)Ain;
        #pragma unroll
        for (int i = 0; i < 4; ++i) {
            int cch = t + i * 256;
            int r = cch >> 4, off = (cch & 15) << 3;
            ushort8v v = *(const ushort8v*)&Xu[(size_t)(row0 + r) * 128 + off];
            *(ushort8v*)&As[(r * 128 + off) ^ ((r & 7) << 3)] = v;
        }
    } else {
        const float* Xf = (const float*)Ain;
        #pragma unroll
        for (int i = 0; i < 4; ++i) {
            int cch = t + i * 256;
            int r = cch >> 4, off = (cch & 15) << 3;
            float4 f0 = *(const float4*)&Xf[(size_t)(row0 + r) * 128 + off];
            float4 f1 = *(const float4*)&Xf[(size_t)(row0 + r) * 128 + off + 4];
            float fv[8] = {f0.x, f0.y, f0.z, f0.w, f1.x, f1.y, f1.z, f1.w};
            ushort8v o;
            #pragma unroll
            for (int j = 0; j < 8; ++j) {
                float v = fv[j];
                if (TRANS) v = fmaxf(0.f, fmaf(v, aT[off + j], bT[off + j]));
                o[j] = f2b(v);
            }
            *(ushort8v*)&As[(r * 128 + off) ^ ((r & 7) << 3)] = o;
        }
    }
    __syncthreads();

    const int w = t >> 6, lane = t & 63;
    const int la = lane & 15, lb = lane >> 4;

    // A fragments: row = w*16 + la, k = s*32 + lb*8 + j
    const int ar = (w << 4) + la;
    const int abase = ar * 128 + lb * 8;
    const int aswz = (ar & 7) << 3;
    bf16x8v afrag[4];
    #pragma unroll
    for (int s = 0; s < 4; ++s)
        afrag[s] = *(const bf16x8v*)&As[(abase + (s << 5)) ^ aswz];

    f32x4v acc[8];
    #pragma unroll
    for (int c = 0; c < 8; ++c) acc[c] = (f32x4v){0.f, 0.f, 0.f, 0.f};

    #pragma unroll
    for (int c = 0; c < 8; ++c) {
        int bn_ = (c << 4) + la;
        int bbase = bn_ * 128 + lb * 8;
        int bswz = (bn_ & 7) << 3;
        #pragma unroll
        for (int s = 0; s < 4; ++s) {
            bf16x8v bfrag = *(const bf16x8v*)&Bs[(bbase + (s << 5)) ^ bswz];
            acc[c] = __builtin_amdgcn_mfma_f32_16x16x32_bf16(afrag[s], bfrag, acc[c], 0, 0, 0);
        }
    }

    // ---- epilogue: bias, write, column stats
    const int orow0 = row0 + (w << 4) + lb * 4;
    float rsj[4];
    if (RSC) {
        #pragma unroll
        for (int j = 0; j < 4; ++j) rsj[j] = rowscale[orow0 + j];
    }
    float csum[8], csq[8];
    #pragma unroll
    for (int c = 0; c < 8; ++c) {
        int col = (c << 4) + la;
        float bc = bias[col];
        float s0 = 0.f, s1 = 0.f;
        #pragma unroll
        for (int j = 0; j < 4; ++j) {
            float v = acc[c][j] + (RSC ? rsj[j] * bc : bc);
            Out[(size_t)(orow0 + j) * 128 + col] = v;
            s0 += v; s1 += v * v;
        }
        csum[c] = s0; csq[c] = s1;
    }
    #pragma unroll
    for (int c = 0; c < 8; ++c) {
        csum[c] += __shfl_xor(csum[c], 16);
        csum[c] += __shfl_xor(csum[c], 32);
        csq[c]  += __shfl_xor(csq[c], 16);
        csq[c]  += __shfl_xor(csq[c], 32);
    }
    if (lane < 16) {
        #pragma unroll
        for (int c = 0; c < 8; ++c) {
            redS[w][(c << 4) + lane] = csum[c];
            redQ[w][(c << 4) + lane] = csq[c];
        }
    }
    __syncthreads();
    if (t < 128) {
        atomicAdd(&stats_out[t], redS[0][t] + redS[1][t] + redS[2][t] + redS[3][t]);
        atomicAdd(&stats_out[128 + t], redQ[0][t] + redQ[1][t] + redQ[2][t] + redQ[3][t]);
    }
}

// ---------------------------------------------------------------------------
// Combine: Yb(bf16) = relu( bn(ZN) + bn(AG) + bn_analytic(ea from s,c) )
// ---------------------------------------------------------------------------
__global__ __launch_bounds__(256) void combine_kernel(
    const float* __restrict__ ZN, const float* __restrict__ AG,
    const float* __restrict__ s, const float* __restrict__ c,
    const float* __restrict__ stZN, const float* __restrict__ gn, const float* __restrict__ btn,
    const float* __restrict__ stAG, const float* __restrict__ gnb, const float* __restrict__ btnb,
    const float* __restrict__ scal, const float* __restrict__ We, const float* __restrict__ Be,
    const float* __restrict__ ge, const float* __restrict__ bte,
    unsigned short* __restrict__ Yb)
{
    __shared__ float A1[128], B1[128], A2[128], B2[128], AE[128], BE[128], CE[128];
    int t = threadIdx.x;
    if (t < 128) {
        float m = stZN[t] * RCP_N;
        float v = stZN[128 + t] * RCP_N - m * m;
        float a = gn[t] * rsqrtf(v + BN_EPS);
        A1[t] = a; B1[t] = btn[t] - m * a;

        m = stAG[t] * RCP_N;
        v = stAG[128 + t] * RCP_N - m * m;
        a = gnb[t] * rsqrtf(v + BN_EPS);
        A2[t] = a; B2[t] = btnb[t] - m * a;

        float ms = scal[0] * RCP_N, vs = scal[1] * RCP_N - ms * ms;
        float mc = scal[2] * RCP_N, vc = scal[3] * RCP_N - mc * mc;
        float cov = scal[4] * RCP_N - ms * mc;
        float we = We[t], be = Be[t];
        float me = ms * we + mc * be;
        float ve = we * we * vs + be * be * vc + 2.f * we * be * cov;
        a = ge[t] * rsqrtf(ve + BN_EPS);
        AE[t] = we * a; BE[t] = be * a; CE[t] = bte[t] - me * a;
    }
    __syncthreads();
    int stride = gridDim.x * 256;
    for (int idx = blockIdx.x * 256 + t; idx < N_NODES * 32; idx += stride) {
        int r = idx >> 5;
        int q = (idx & 31) * 4;
        float4 zn = *(const float4*)&ZN[(size_t)r * 128 + q];
        float4 ag = *(const float4*)&AG[(size_t)r * 128 + q];
        float sr = s[r], cr = c[r];
        float y0 = fmaxf(0.f, zn.x * A1[q]     + B1[q]     + ag.x * A2[q]     + B2[q]     + sr * AE[q]     + cr * BE[q]     + CE[q]);
        float y1 = fmaxf(0.f, zn.y * A1[q + 1] + B1[q + 1] + ag.y * A2[q + 1] + B2[q + 1] + sr * AE[q + 1] + cr * BE[q + 1] + CE[q + 1]);
        float y2 = fmaxf(0.f, zn.z * A1[q + 2] + B1[q + 2] + ag.z * A2[q + 2] + B2[q + 2] + sr * AE[q + 2] + cr * BE[q + 2] + CE[q + 2]);
        float y3 = fmaxf(0.f, zn.w * A1[q + 3] + B1[q + 3] + ag.w * A2[q + 3] + B2[q + 3] + sr * AE[q + 3] + cr * BE[q + 3] + CE[q + 3]);
        ushort4 o;
        o.x = f2b(y0); o.y = f2b(y1); o.z = f2b(y2); o.w = f2b(y3);
        *(ushort4*)&Yb[(size_t)r * 128 + q] = o;
    }
}

// Elementwise relu(bn(Z)) -> bf16 (BF16OUT) or f32
template<bool BF16OUT>
__global__ __launch_bounds__(256) void bnrelu_kernel(
    const float* __restrict__ Z, const float* __restrict__ stz,
    const float* __restrict__ g, const float* __restrict__ bt,
    float* __restrict__ Of, unsigned short* __restrict__ Ob)
{
    __shared__ float aT[128], bT[128];
    int t = threadIdx.x;
    if (t < 128) {
        float m = stz[t] * RCP_N;
        float v = stz[128 + t] * RCP_N - m * m;
        float a = g[t] * rsqrtf(v + BN_EPS);
        aT[t] = a; bT[t] = bt[t] - m * a;
    }
    __syncthreads();
    int stride = gridDim.x * 256;
    for (int idx = blockIdx.x * 256 + t; idx < N_NODES * 32; idx += stride) {
        int r = idx >> 5;
        int q = (idx & 31) * 4;
        float4 z = *(const float4*)&Z[(size_t)r * 128 + q];
        float o0 = fmaxf(0.f, fmaf(z.x, aT[q],     bT[q]));
        float o1 = fmaxf(0.f, fmaf(z.y, aT[q + 1], bT[q + 1]));
        float o2 = fmaxf(0.f, fmaf(z.z, aT[q + 2], bT[q + 2]));
        float o3 = fmaxf(0.f, fmaf(z.w, aT[q + 3], bT[q + 3]));
        if (BF16OUT) {
            ushort4 o;
            o.x = f2b(o0); o.y = f2b(o1); o.z = f2b(o2); o.w = f2b(o3);
            *(ushort4*)&Ob[(size_t)r * 128 + q] = o;
        } else {
            float4 o = {o0, o1, o2, o3};
            *(float4*)&Of[(size_t)r * 128 + q] = o;
        }
    }
}

// ---------------------------------------------------------------------------
extern "C" void kernel_launch(void* const* d_in, const int* in_sizes, int n_in,
                              void* d_out, int out_size, void* d_ws, size_t ws_size,
                              hipStream_t stream)
{
    const float* node_attr = (const float*)d_in[0];
    const int*   ei        = (const int*)d_in[1];
    const float* ea        = (const float*)d_in[2];
    const float* W0    = (const float*)d_in[3];
    const float* b0    = (const float*)d_in[4];
    const float* g0    = (const float*)d_in[5];
    const float* bt0   = (const float*)d_in[6];
    const float* Wnode = (const float*)d_in[7];
    const float* bnode = (const float*)d_in[8];
    const float* Wedge = (const float*)d_in[9];
    const float* bedge = (const float*)d_in[10];
    const float* Wnb   = (const float*)d_in[11];
    const float* bnb   = (const float*)d_in[12];
    const float* gn    = (const float*)d_in[13];
    const float* ge    = (const float*)d_in[14];
    const float* gnb   = (const float*)d_in[15];
    const float* gm1   = (const float*)d_in[16];
    const float* gm2   = (const float*)d_in[17];
    const float* btn   = (const float*)d_in[18];
    const float* bte   = (const float*)d_in[19];
    const float* btnb  = (const float*)d_in[20];
    const float* btm1  = (const float*)d_in[21];
    const float* btm2  = (const float*)d_in[22];
    const float* Wm1   = (const float*)d_in[23];
    const float* bm1   = (const float*)d_in[24];
    const float* Wm2   = (const float*)d_in[25];
    const float* bm2   = (const float*)d_in[26];
    float* out = (float*)d_out;

    // workspace layout (floats):
    // P(NF) | ZN(NF) | G(NF) | Bb(NF bf16 = NF/2) | sN | cN | dg | st(4096)
    // | startA(N+64 int) | cursor(N int) | csr(E int) | Wt(12*16384 bf16)
    float* ws = (float*)d_ws;
    float* P  = ws;
    float* ZN = ws + NF;
    float* G  = ws + 2 * NF;
    unsigned short* Bb = (unsigned short*)(ws + 3 * NF);
    float* sN = ws + 3 * NF + NF / 2;
    float* cN = sN + N_NODES;
    float* dg = cN + N_NODES;
    float* st = dg + N_NODES;
    int* startA = (int*)(st + 4096);
    int* cursor = startA + N_NODES + 64;
    int* csr    = cursor + N_NODES;
    unsigned short* Wtb = (unsigned short*)(csr + N_EDGES);
    // stats: [0..255] z0 | [256..263] scalar5 | layer i at 264+i*1024:
    //   zn(+0), aggr(+256), z1(+512), z2(+768)

    // zero sN,cN,dg,st and cursor (memset spans startA too — rewritten by scan)
    hipMemsetAsync(sN, 0, (size_t)(5 * N_NODES + 4096 + 64 + 1) * sizeof(float), stream);
    wprep_kernel<<<48, 256, 0, stream>>>(Wnode, Wnb, Wm1, Wm2, Wtb);
    edge_scalar_kernel<<<1024, 256, 0, stream>>>(ei, ea, sN, cN, dg);
    scalar_stats_kernel<<<160, 256, 0, stream>>>(sN, cN, st + 256);
    scan_kernel<<<1, 256, 0, stream>>>(dg, startA);
    bucket_kernel<<<1024, 256, 0, stream>>>(ei, startA, cursor, csr);
    init_node_kernel<<<625, 256, 0, stream>>>(node_attr, W0, b0, P, st);

    const float* xst = st;
    const float* xg  = g0;
    const float* xbt = bt0;

    for (int i = 0; i < 3; ++i) {
        float* lay = st + 264 + i * 1024;
        // Xb = relu(bn(P)) as bf16
        bnrelu_kernel<true><<<2048, 256, 0, stream>>>(P, xst, xg, xbt, nullptr, Bb);
        // neighbor aggregation (raw f32 sums of bf16 rows)
        gather_kernel<<<10000, 256, 0, stream>>>(startA, csr, Bb, G);
        // node branch: ZN = Xb @ Wnode + bnode (+stats)
        mfma_gemm_kernel<false, false, false><<<625, 256, 0, stream>>>(
            Bb, Wtb + (size_t)(0 + i) * 16384, bnode + i * 128, nullptr,
            nullptr, nullptr, nullptr, ZN, lay);
        // neighbor branch: G = G @ Wnb + deg*bnb (+stats), in place
        mfma_gemm_kernel<true, false, true><<<625, 256, 0, stream>>>(
            G, Wtb + (size_t)(3 + i) * 16384, bnb + i * 128, dg,
            nullptr, nullptr, nullptr, G, lay + 256);
        // Yb = relu(bn(ZN) + bn(G) + ea) as bf16 (into Bb; Xb is dead)
        combine_kernel<<<2048, 256, 0, stream>>>(
            ZN, G, sN, cN,
            lay, gn + i * 128, btn + i * 128,
            lay + 256, gnb + i * 128, btnb + i * 128,
            st + 256, Wedge + i * 128, bedge + i * 128, ge + i * 128, bte + i * 128,
            Bb);
        // z1 = Yb @ Wm1 + bm1 (+stats) -> ZN
        mfma_gemm_kernel<false, false, false><<<625, 256, 0, stream>>>(
            Bb, Wtb + (size_t)(6 + i) * 16384, bm1 + i * 128, nullptr,
            nullptr, nullptr, nullptr, ZN, lay + 512);
        // z2 = relu(bn(z1)) @ Wm2 + bm2 (+stats) -> P
        mfma_gemm_kernel<true, true, false><<<625, 256, 0, stream>>>(
            ZN, Wtb + (size_t)(9 + i) * 16384, bm2 + i * 128, nullptr,
            lay + 512, gm1 + i * 128, btm1 + i * 128, P, lay + 768);

        xst = lay + 768;
        xg  = gm2 + i * 128;
        xbt = btm2 + i * 128;
    }
    bnrelu_kernel<false><<<2048, 256, 0, stream>>>(P, xst, xg, xbt, out, nullptr);
}

// Round 4
// 766.300 us; speedup vs baseline: 2.9661x; 1.0184x over previous
//
#include <hip/hip_runtime.h>

#define N_NODES 40000
#define N_EDGES 640000
#define EMB 128
#define NF ((size_t)N_NODES * EMB)
#define RCP_N (1.0f / (float)N_NODES)
#define BN_EPS 1e-5f

typedef __bf16 bf16x8v __attribute__((ext_vector_type(8)));
typedef float f32x4v __attribute__((ext_vector_type(4)));
typedef unsigned short ushort8v __attribute__((ext_vector_type(8)));

__device__ __forceinline__ unsigned short f2b(float v) {
    return __builtin_bit_cast(unsigned short, (__bf16)v);
}

// ---------------------------------------------------------------------------
// Per-edge pass: ONE u64 atomic packs (s,c) by row; u32 histogram for deg(col).
//   u64 add = ((fx + 2^30) << 20) | 1,  fx = rint(ea * 65536)
//   decode: cnt = v & 0xFFFFF;  sum_fx = (v>>20) - cnt*2^30
// ---------------------------------------------------------------------------
__global__ __launch_bounds__(256) void edge_pack_kernel(
    const int* __restrict__ ei, const float* __restrict__ ea,
    unsigned long long* __restrict__ scP, unsigned* __restrict__ degc)
{
    int e = blockIdx.x * 256 + threadIdx.x;   // grid = 2500*256 == N_EDGES
    int r = ei[e];
    int d = ei[N_EDGES + e];
    int fx = (int)rintf(ea[e] * 65536.0f);
    unsigned long long add =
        (((unsigned long long)(unsigned)(fx + 0x40000000)) << 20) | 1ULL;
    atomicAdd(&scP[r], add);
    atomicAdd(&degc[d], 1u);
}

// Decode scP -> sN, cN (f32) and scalar moments {Σs, Σs², Σc, Σc², Σsc}
__global__ __launch_bounds__(256) void decode_kernel(
    const unsigned long long* __restrict__ scP,
    float* __restrict__ sN, float* __restrict__ cN, float* __restrict__ mom)
{
    int idx = blockIdx.x * 256 + threadIdx.x;
    int stride = gridDim.x * 256;
    float a0 = 0.f, a1 = 0.f, a2 = 0.f, a3 = 0.f, a4 = 0.f;
    for (int r = idx; r < N_NODES; r += stride) {
        unsigned long long v = scP[r];
        unsigned cnt = (unsigned)(v & 0xFFFFFULL);
        long long sp = (long long)(v >> 20) - ((long long)cnt << 30);
        float s = (float)sp * (1.0f / 65536.0f);
        float c = (float)cnt;
        sN[r] = s; cN[r] = c;
        a0 += s; a1 += s * s; a2 += c; a3 += c * c; a4 += s * c;
    }
    #pragma unroll
    for (int off = 32; off > 0; off >>= 1) {
        a0 += __shfl_down(a0, off);
        a1 += __shfl_down(a1, off);
        a2 += __shfl_down(a2, off);
        a3 += __shfl_down(a3, off);
        a4 += __shfl_down(a4, off);
    }
    if ((threadIdx.x & 63) == 0) {
        atomicAdd(&mom[0], a0);
        atomicAdd(&mom[1], a1);
        atomicAdd(&mom[2], a2);
        atomicAdd(&mom[3], a3);
        atomicAdd(&mom[4], a4);
    }
}

// ---------------------------------------------------------------------------
// CSR build: exclusive scan of in-degrees (also emits f32 deg), bucket fill.
// ---------------------------------------------------------------------------
__global__ __launch_bounds__(256) void scan_kernel(
    const unsigned* __restrict__ degc, int* __restrict__ start,
    float* __restrict__ dgf)
{
    __shared__ int partials[256];
    int t = threadIdx.x;
    const int CHUNK = (N_NODES + 255) / 256;
    int b0 = t * CHUNK;
    int b1 = min(b0 + CHUNK, N_NODES);
    int lsum = 0;
    for (int i = b0; i < b1; ++i) lsum += (int)degc[i];
    partials[t] = lsum;
    __syncthreads();
    for (int off = 1; off < 256; off <<= 1) {
        int v = (t >= off) ? partials[t - off] : 0;
        __syncthreads();
        partials[t] += v;
        __syncthreads();
    }
    int prefix = (t == 0) ? 0 : partials[t - 1];
    for (int i = b0; i < b1; ++i) {
        int d = (int)degc[i];
        start[i] = prefix;
        dgf[i] = (float)d;
        prefix += d;
    }
    if (t == 255) start[N_NODES] = prefix;
}

__global__ __launch_bounds__(256) void bucket_kernel(
    const int* __restrict__ ei, const int* __restrict__ start,
    int* __restrict__ cursor, int* __restrict__ csr)
{
    int e = blockIdx.x * 256 + threadIdx.x;   // grid = 2500*256 == N_EDGES
    int r = ei[e];
    int d = ei[N_EDGES + e];
    int pos = atomicAdd(&cursor[d], 1);
    csr[start[d] + pos] = r;
}

// ---------------------------------------------------------------------------
// Gather with inline bn+relu: G[d] = sum over in-edges of relu(a*P[src]+b)
// One wave per node, float2 per lane, f32 throughout.
// ---------------------------------------------------------------------------
__global__ __launch_bounds__(256) void gather_bn_kernel(
    const int* __restrict__ start, const int* __restrict__ csr,
    const float* __restrict__ P,
    const float* __restrict__ stats_in, const float* __restrict__ g_in,
    const float* __restrict__ bt_in,
    float* __restrict__ G)
{
    __shared__ float aT[128], bT[128];
    int t = threadIdx.x;
    if (t < 128) {
        float m = stats_in[t] * RCP_N;
        float v = stats_in[128 + t] * RCP_N - m * m;
        float a = g_in[t] * rsqrtf(v + BN_EPS);
        aT[t] = a; bT[t] = bt_in[t] - m * a;
    }
    __syncthreads();
    int wid = (blockIdx.x * 256 + t) >> 6;
    int lane = t & 63;
    if (wid >= N_NODES) return;
    float a0 = aT[2 * lane], b0 = bT[2 * lane];
    float a1 = aT[2 * lane + 1], b1 = bT[2 * lane + 1];
    int e0 = start[wid], e1 = start[wid + 1];
    float s0 = 0.f, s1 = 0.f, s2 = 0.f, s3 = 0.f;
    int e = e0;
    for (; e + 1 < e1; e += 2) {
        int r0 = csr[e], r1 = csr[e + 1];
        float2 v0 = *(const float2*)&P[(size_t)r0 * 128 + 2 * lane];
        float2 v1 = *(const float2*)&P[(size_t)r1 * 128 + 2 * lane];
        s0 += fmaxf(0.f, fmaf(v0.x, a0, b0));
        s1 += fmaxf(0.f, fmaf(v0.y, a1, b1));
        s2 += fmaxf(0.f, fmaf(v1.x, a0, b0));
        s3 += fmaxf(0.f, fmaf(v1.y, a1, b1));
    }
    if (e < e1) {
        float2 v0 = *(const float2*)&P[(size_t)csr[e] * 128 + 2 * lane];
        s0 += fmaxf(0.f, fmaf(v0.x, a0, b0));
        s1 += fmaxf(0.f, fmaf(v0.y, a1, b1));
    }
    float2 o = {s0 + s2, s1 + s3};
    *(float2*)&G[(size_t)wid * 128 + 2 * lane] = o;
}

// ---------------------------------------------------------------------------
// Initial node MLP pre-activation: Z = node_attr @ W0 + b0 (K=2), + col stats
// ---------------------------------------------------------------------------
__global__ __launch_bounds__(256) void init_node_kernel(
    const float* __restrict__ na, const float* __restrict__ W0,
    const float* __restrict__ b0, float* __restrict__ Z, float* __restrict__ st)
{
    int t = threadIdx.x;
    int col = t & 127, rh = t >> 7;
    float w0 = W0[col], w1 = W0[128 + col], bb = b0[col];
    int rbase = blockIdx.x * 64;
    float sm = 0.f, sq = 0.f;
    #pragma unroll 4
    for (int i = 0; i < 32; ++i) {
        int r = rbase + rh + i * 2;
        float2 nv = *(const float2*)&na[r * 2];
        float v = fmaf(nv.x, w0, fmaf(nv.y, w1, bb));
        Z[(size_t)r * 128 + col] = v;
        sm += v; sq += v * v;
    }
    __shared__ float red[256];
    red[t] = sm; __syncthreads();
    if (t < 128) atomicAdd(&st[t], red[t] + red[t + 128]);
    __syncthreads();
    red[t] = sq; __syncthreads();
    if (t < 128) atomicAdd(&st[128 + t], red[t] + red[t + 128]);
}

// ---------------------------------------------------------------------------
// Weight prep: Wt[mat][n][k] = bf16(W[mat][k][n]), 12 matrices of 128x128.
// ---------------------------------------------------------------------------
__global__ __launch_bounds__(256) void wprep_kernel(
    const float* __restrict__ Wnode, const float* __restrict__ Wnb,
    const float* __restrict__ Wm1, const float* __restrict__ Wm2,
    unsigned short* __restrict__ Wt)
{
    __shared__ float tile[32][129];
    int b = blockIdx.x;
    int mat = b >> 2, kc = (b & 3) * 32;
    int grp = mat / 3, lay = mat % 3;
    const float* src = (grp == 0) ? Wnode : (grp == 1) ? Wnb : (grp == 2) ? Wm1 : Wm2;
    src += (size_t)lay * 16384;
    int t = threadIdx.x;
    #pragma unroll
    for (int i = 0; i < 16; ++i) {
        int idx = t + i * 256;
        int r = idx >> 7, n = idx & 127;
        tile[r][n] = src[(size_t)(kc + r) * 128 + n];
    }
    __syncthreads();
    int n = t >> 1, h = (t & 1) * 16;
    ushort8v o0, o1;
    #pragma unroll
    for (int j = 0; j < 8; ++j) o0[j] = f2b(tile[h + j][n]);
    #pragma unroll
    for (int j = 0; j < 8; ++j) o1[j] = f2b(tile[h + 8 + j][n]);
    unsigned short* dst = &Wt[(size_t)mat * 16384 + n * 128 + kc + h];
    *(ushort8v*)dst = o0;
    *(ushort8v*)(dst + 8) = o1;
}

// ---------------------------------------------------------------------------
// MFMA GEMM: Out[N,128] = T(A...)[N,128] @ W[128,128] + bias, + column stats.
//   AMODE 0: A f32 plain
//   AMODE 1: A f32 with relu(a*x+b) from (st1, g1, bt1)
//   AMODE 2: fused combine: T = relu(bn(A;st1,g1,bt1) + bn(A2;st2,g2,bt2)
//                                 + analytic edge bn from (scal,We,Be,ge,bte))
//   RSC: bias scaled per-row by rowscale[r]
// 64-row tiles (grid 625), 256 threads = 4 waves, wave = 16 rows x 128 cols.
// In-place safe: each block reads only its own 64 rows into LDS before writes.
// ---------------------------------------------------------------------------
template<int AMODE, bool RSC>
__global__ __launch_bounds__(256) void mfma_gemm_kernel(
    const float* __restrict__ A, const float* __restrict__ A2,
    const unsigned short* __restrict__ Wt,
    const float* __restrict__ bias, const float* __restrict__ rowscale,
    const float* __restrict__ st1, const float* __restrict__ g1, const float* __restrict__ bt1,
    const float* __restrict__ st2, const float* __restrict__ g2, const float* __restrict__ bt2,
    const float* __restrict__ sN, const float* __restrict__ cN,
    const float* __restrict__ scal,
    const float* __restrict__ We, const float* __restrict__ Be,
    const float* __restrict__ ge, const float* __restrict__ bte,
    float* __restrict__ Out, float* __restrict__ stats_out)
{
    __shared__ __align__(16) unsigned short As[64 * 128];   // swizzled bf16
    __shared__ __align__(16) unsigned short Bs[128 * 128];  // swizzled bf16 W^T
    __shared__ float C1[128], D1[128], C2[128], D2[128];
    __shared__ float AE[128], BE[128], CE[128];
    __shared__ float redS[4][128], redQ[4][128];

    const int t = threadIdx.x;
    const int row0 = blockIdx.x * 64;

    if (AMODE == 1) {
        if (t < 128) {
            float m = st1[t] * RCP_N;
            float v = st1[128 + t] * RCP_N - m * m;
            float a = g1[t] * rsqrtf(v + BN_EPS);
            C1[t] = a; D1[t] = bt1[t] - m * a;
        }
        __syncthreads();
    } else if (AMODE == 2) {
        if (t < 128) {
            float m = st1[t] * RCP_N;
            float v = st1[128 + t] * RCP_N - m * m;
            float a = g1[t] * rsqrtf(v + BN_EPS);
            C1[t] = a; D1[t] = bt1[t] - m * a;

            m = st2[t] * RCP_N;
            v = st2[128 + t] * RCP_N - m * m;
            a = g2[t] * rsqrtf(v + BN_EPS);
            C2[t] = a; D2[t] = bt2[t] - m * a;

            float ms = scal[0] * RCP_N, vs = scal[1] * RCP_N - ms * ms;
            float mc = scal[2] * RCP_N, vc = scal[3] * RCP_N - mc * mc;
            float cov = scal[4] * RCP_N - ms * mc;
            float we = We[t], be = Be[t];
            float me = ms * we + mc * be;
            float ve = we * we * vs + be * be * vc + 2.f * we * be * cov;
            a = ge[t] * rsqrtf(ve + BN_EPS);
            AE[t] = we * a; BE[t] = be * a; CE[t] = bte[t] - me * a;
        }
        __syncthreads();
    }

    // ---- stage B (W^T bf16, 128x128) with XOR swizzle
    #pragma unroll
    for (int i = 0; i < 8; ++i) {
        int cch = t + i * 256;
        int n = cch >> 4, off = (cch & 15) << 3;
        ushort8v w = *(const ushort8v*)&Wt[n * 128 + off];
        *(ushort8v*)&Bs[(n * 128 + off) ^ ((n & 7) << 3)] = w;
    }
    // ---- stage A (64x128 f32 -> transformed bf16) with XOR swizzle
    #pragma unroll
    for (int i = 0; i < 4; ++i) {
        int cch = t + i * 256;
        int r = cch >> 4, off = (cch & 15) << 3;
        const float* Ar = &A[(size_t)(row0 + r) * 128 + off];
        float4 f0 = *(const float4*)Ar;
        float4 f1 = *(const float4*)(Ar + 4);
        float fv[8] = {f0.x, f0.y, f0.z, f0.w, f1.x, f1.y, f1.z, f1.w};
        ushort8v o;
        if (AMODE == 2) {
            const float* Gr = &A2[(size_t)(row0 + r) * 128 + off];
            float4 g0v = *(const float4*)Gr;
            float4 g1v = *(const float4*)(Gr + 4);
            float gv[8] = {g0v.x, g0v.y, g0v.z, g0v.w, g1v.x, g1v.y, g1v.z, g1v.w};
            float sr = sN[row0 + r], cr = cN[row0 + r];
            #pragma unroll
            for (int j = 0; j < 8; ++j) {
                int q = off + j;
                float y = fv[j] * C1[q] + D1[q] + gv[j] * C2[q] + D2[q]
                        + sr * AE[q] + cr * BE[q] + CE[q];
                o[j] = f2b(fmaxf(0.f, y));
            }
        } else {
            #pragma unroll
            for (int j = 0; j < 8; ++j) {
                float v = fv[j];
                if (AMODE == 1) v = fmaxf(0.f, fmaf(v, C1[off + j], D1[off + j]));
                o[j] = f2b(v);
            }
        }
        *(ushort8v*)&As[(r * 128 + off) ^ ((r & 7) << 3)] = o;
    }
    __syncthreads();

    const int w = t >> 6, lane = t & 63;
    const int la = lane & 15, lb = lane >> 4;

    const int ar = (w << 4) + la;
    const int abase = ar * 128 + lb * 8;
    const int aswz = (ar & 7) << 3;
    bf16x8v afrag[4];
    #pragma unroll
    for (int s = 0; s < 4; ++s)
        afrag[s] = *(const bf16x8v*)&As[(abase + (s << 5)) ^ aswz];

    f32x4v acc[8];
    #pragma unroll
    for (int c = 0; c < 8; ++c) acc[c] = (f32x4v){0.f, 0.f, 0.f, 0.f};

    #pragma unroll
    for (int c = 0; c < 8; ++c) {
        int bn_ = (c << 4) + la;
        int bbase = bn_ * 128 + lb * 8;
        int bswz = (bn_ & 7) << 3;
        #pragma unroll
        for (int s = 0; s < 4; ++s) {
            bf16x8v bfrag = *(const bf16x8v*)&Bs[(bbase + (s << 5)) ^ bswz];
            acc[c] = __builtin_amdgcn_mfma_f32_16x16x32_bf16(afrag[s], bfrag, acc[c], 0, 0, 0);
        }
    }

    // ---- epilogue: bias, write, column stats
    const int orow0 = row0 + (w << 4) + lb * 4;
    float rsj[4];
    if (RSC) {
        #pragma unroll
        for (int j = 0; j < 4; ++j) rsj[j] = rowscale[orow0 + j];
    }
    float csum[8], csq[8];
    #pragma unroll
    for (int c = 0; c < 8; ++c) {
        int col = (c << 4) + la;
        float bc = bias[col];
        float s0 = 0.f, s1 = 0.f;
        #pragma unroll
        for (int j = 0; j < 4; ++j) {
            float v = acc[c][j] + (RSC ? rsj[j] * bc : bc);
            Out[(size_t)(orow0 + j) * 128 + col] = v;
            s0 += v; s1 += v * v;
        }
        csum[c] = s0; csq[c] = s1;
    }
    #pragma unroll
    for (int c = 0; c < 8; ++c) {
        csum[c] += __shfl_xor(csum[c], 16);
        csum[c] += __shfl_xor(csum[c], 32);
        csq[c]  += __shfl_xor(csq[c], 16);
        csq[c]  += __shfl_xor(csq[c], 32);
    }
    if (lane < 16) {
        #pragma unroll
        for (int c = 0; c < 8; ++c) {
            redS[w][(c << 4) + lane] = csum[c];
            redQ[w][(c << 4) + lane] = csq[c];
        }
    }
    __syncthreads();
    if (t < 128) {
        atomicAdd(&stats_out[t], redS[0][t] + redS[1][t] + redS[2][t] + redS[3][t]);
        atomicAdd(&stats_out[128 + t], redQ[0][t] + redQ[1][t] + redQ[2][t] + redQ[3][t]);
    }
}

// Final elementwise: out = relu(bn(Z)) f32
__global__ __launch_bounds__(256) void bnrelu_kernel(
    const float* __restrict__ Z, const float* __restrict__ stz,
    const float* __restrict__ g, const float* __restrict__ bt,
    float* __restrict__ O)
{
    __shared__ float aT[128], bT[128];
    int t = threadIdx.x;
    if (t < 128) {
        float m = stz[t] * RCP_N;
        float v = stz[128 + t] * RCP_N - m * m;
        float a = g[t] * rsqrtf(v + BN_EPS);
        aT[t] = a; bT[t] = bt[t] - m * a;
    }
    __syncthreads();
    int stride = gridDim.x * 256;
    for (int idx = blockIdx.x * 256 + t; idx < N_NODES * 32; idx += stride) {
        int r = idx >> 5;
        int q = (idx & 31) * 4;
        float4 z = *(const float4*)&Z[(size_t)r * 128 + q];
        float4 o;
        o.x = fmaxf(0.f, fmaf(z.x, aT[q],     bT[q]));
        o.y = fmaxf(0.f, fmaf(z.y, aT[q + 1], bT[q + 1]));
        o.z = fmaxf(0.f, fmaf(z.z, aT[q + 2], bT[q + 2]));
        o.w = fmaxf(0.f, fmaf(z.w, aT[q + 3], bT[q + 3]));
        *(float4*)&O[(size_t)r * 128 + q] = o;
    }
}

// ---------------------------------------------------------------------------
extern "C" void kernel_launch(void* const* d_in, const int* in_sizes, int n_in,
                              void* d_out, int out_size, void* d_ws, size_t ws_size,
                              hipStream_t stream)
{
    const float* node_attr = (const float*)d_in[0];
    const int*   ei        = (const int*)d_in[1];
    const float* ea        = (const float*)d_in[2];
    const float* W0    = (const float*)d_in[3];
    const float* b0    = (const float*)d_in[4];
    const float* g0    = (const float*)d_in[5];
    const float* bt0   = (const float*)d_in[6];
    const float* Wnode = (const float*)d_in[7];
    const float* bnode = (const float*)d_in[8];
    const float* Wedge = (const float*)d_in[9];
    const float* bedge = (const float*)d_in[10];
    const float* Wnb   = (const float*)d_in[11];
    const float* bnb   = (const float*)d_in[12];
    const float* gn    = (const float*)d_in[13];
    const float* ge    = (const float*)d_in[14];
    const float* gnb   = (const float*)d_in[15];
    const float* gm1   = (const float*)d_in[16];
    const float* gm2   = (const float*)d_in[17];
    const float* btn   = (const float*)d_in[18];
    const float* bte   = (const float*)d_in[19];
    const float* btnb  = (const float*)d_in[20];
    const float* btm1  = (const float*)d_in[21];
    const float* btm2  = (const float*)d_in[22];
    const float* Wm1   = (const float*)d_in[23];
    const float* bm1   = (const float*)d_in[24];
    const float* Wm2   = (const float*)d_in[25];
    const float* bm2   = (const float*)d_in[26];
    float* out = (float*)d_out;

    // workspace (floats):
    // P(NF) | ZN(NF) | G(NF) | sN | cN | dg | st(4096) | scP(u64,40000)
    // | degc(u32,40000) | cursor(40000) | startA(40064) | csr(E) | Wtb(bf16)
    float* ws = (float*)d_ws;
    float* P  = ws;
    float* ZN = ws + NF;
    float* G  = ws + 2 * NF;
    float* sN = ws + 3 * NF;
    float* cN = sN + N_NODES;
    float* dg = cN + N_NODES;
    float* st = dg + N_NODES;
    unsigned long long* scP = (unsigned long long*)(st + 4096);
    unsigned* degc = (unsigned*)(scP + N_NODES);
    int* cursor = (int*)(degc + N_NODES);
    int* startA = cursor + N_NODES;
    int* csr    = startA + N_NODES + 64;
    unsigned short* Wtb = (unsigned short*)(csr + N_EDGES);
    // stats: st[0..255] init | st[256..260] scalar moments | layer i at
    //   264+i*1024: zn(+0), aggr(+256), z1(+512), z2(+768)

    // zero st | scP | degc | cursor (contiguous)
    hipMemsetAsync(st, 0, (size_t)(4096 + 2 * N_NODES + 2 * N_NODES) * sizeof(float), stream);
    wprep_kernel<<<48, 256, 0, stream>>>(Wnode, Wnb, Wm1, Wm2, Wtb);
    edge_pack_kernel<<<2500, 256, 0, stream>>>(ei, ea, scP, degc);
    scan_kernel<<<1, 256, 0, stream>>>(degc, startA, dg);
    decode_kernel<<<160, 256, 0, stream>>>(scP, sN, cN, st + 256);
    bucket_kernel<<<2500, 256, 0, stream>>>(ei, startA, cursor, csr);
    init_node_kernel<<<625, 256, 0, stream>>>(node_attr, W0, b0, P, st);

    const float* xst = st;
    const float* xg  = g0;
    const float* xbt = bt0;

    for (int i = 0; i < 3; ++i) {
        float* lay = st + 264 + i * 1024;
        // G = sum over in-edges of relu(bn(P[src]))
        gather_bn_kernel<<<10000, 256, 0, stream>>>(startA, csr, P, xst, xg, xbt, G);
        // node branch: ZN = relu(bn(P)) @ Wnode + bnode (+stats)
        mfma_gemm_kernel<1, false><<<625, 256, 0, stream>>>(
            P, nullptr, Wtb + (size_t)(0 + i) * 16384, bnode + i * 128, nullptr,
            xst, xg, xbt, nullptr, nullptr, nullptr,
            nullptr, nullptr, nullptr, nullptr, nullptr, nullptr, nullptr,
            ZN, lay);
        // neighbor branch: G = G @ Wnb + deg*bnb (+stats), in place
        mfma_gemm_kernel<0, true><<<625, 256, 0, stream>>>(
            G, nullptr, Wtb + (size_t)(3 + i) * 16384, bnb + i * 128, dg,
            nullptr, nullptr, nullptr, nullptr, nullptr, nullptr,
            nullptr, nullptr, nullptr, nullptr, nullptr, nullptr, nullptr,
            G, lay + 256);
        // z1 = relu(bn(ZN)+bn(G)+ea) @ Wm1 + bm1 (+stats) -> ZN (fused combine)
        mfma_gemm_kernel<2, false><<<625, 256, 0, stream>>>(
            ZN, G, Wtb + (size_t)(6 + i) * 16384, bm1 + i * 128, nullptr,
            lay, gn + i * 128, btn + i * 128,
            lay + 256, gnb + i * 128, btnb + i * 128,
            sN, cN, st + 256,
            Wedge + i * 128, bedge + i * 128, ge + i * 128, bte + i * 128,
            ZN, lay + 512);
        // z2 = relu(bn(z1)) @ Wm2 + bm2 (+stats) -> P
        mfma_gemm_kernel<1, false><<<625, 256, 0, stream>>>(
            ZN, nullptr, Wtb + (size_t)(9 + i) * 16384, bm2 + i * 128, nullptr,
            lay + 512, gm1 + i * 128, btm1 + i * 128, nullptr, nullptr, nullptr,
            nullptr, nullptr, nullptr, nullptr, nullptr, nullptr, nullptr,
            P, lay + 768);

        xst = lay + 768;
        xg  = gm2 + i * 128;
        xbt = btm2 + i * 128;
    }
    bnrelu_kernel<<<2048, 256, 0, stream>>>(P, xst, xg, xbt, out);
}

// Round 5
// 677.873 us; speedup vs baseline: 3.3530x; 1.1304x over previous
//
#include <hip/hip_runtime.h>

#define N_NODES 40000
#define N_EDGES 640000
#define EMB 128
#define NF ((size_t)N_NODES * EMB)
#define RCP_N (1.0f / (float)N_NODES)
#define BN_EPS 1e-5f
#define NB_SCAN 157   // ceil(40000/256)

typedef _Float16 f16x8v __attribute__((ext_vector_type(8)));
typedef float f32x4v __attribute__((ext_vector_type(4)));
typedef unsigned short ushort8v __attribute__((ext_vector_type(8)));

__device__ __forceinline__ unsigned short f2h(float v) {
    return __builtin_bit_cast(unsigned short, (_Float16)v);
}

// ---------------------------------------------------------------------------
// Per-edge pass: ONE u64 atomic packs (s,c) by row; u32 histogram for deg(col).
//   u64 add = ((fx + 2^30) << 20) | 1,  fx = rint(ea * 65536)
// ---------------------------------------------------------------------------
__global__ __launch_bounds__(256) void edge_pack_kernel(
    const int* __restrict__ ei, const float* __restrict__ ea,
    unsigned long long* __restrict__ scP, unsigned* __restrict__ degc)
{
    int e = blockIdx.x * 256 + threadIdx.x;   // grid = 2500*256 == N_EDGES
    int r = ei[e];
    int d = ei[N_EDGES + e];
    int fx = (int)rintf(ea[e] * 65536.0f);
    unsigned long long add =
        (((unsigned long long)(unsigned)(fx + 0x40000000)) << 20) | 1ULL;
    atomicAdd(&scP[r], add);
    atomicAdd(&degc[d], 1u);
}

// ---------------------------------------------------------------------------
// Parallel scan of in-degrees, 3 passes.
// ---------------------------------------------------------------------------
__global__ __launch_bounds__(256) void scan1_kernel(
    const unsigned* __restrict__ degc, int* __restrict__ start,
    int* __restrict__ bsum)
{
    __shared__ int sh[256];
    int t = threadIdx.x, b = blockIdx.x;
    int i = b * 256 + t;
    int v = (i < N_NODES) ? (int)degc[i] : 0;
    sh[t] = v;
    __syncthreads();
    #pragma unroll
    for (int off = 1; off < 256; off <<= 1) {
        int u = (t >= off) ? sh[t - off] : 0;
        __syncthreads();
        sh[t] += u;
        __syncthreads();
    }
    if (i < N_NODES) start[i] = sh[t] - v;   // local exclusive prefix
    if (t == 255) bsum[b] = sh[255];
}

__global__ __launch_bounds__(256) void scan2_kernel(
    const int* __restrict__ bsum, int* __restrict__ boff)
{
    __shared__ int sh[256];
    int t = threadIdx.x;
    int v = (t < NB_SCAN) ? bsum[t] : 0;
    sh[t] = v;
    __syncthreads();
    #pragma unroll
    for (int off = 1; off < 256; off <<= 1) {
        int u = (t >= off) ? sh[t - off] : 0;
        __syncthreads();
        sh[t] += u;
        __syncthreads();
    }
    if (t < NB_SCAN) boff[t] = sh[t] - v;    // exclusive block offset
}

// Pass 3 merged with scP decode: fix up start, emit f32 deg, decode (s,c),
// accumulate scalar moments {Σs, Σs², Σc, Σc², Σsc}.
__global__ __launch_bounds__(256) void scan3_decode_kernel(
    const unsigned* __restrict__ degc, const int* __restrict__ boff,
    int* __restrict__ start, float* __restrict__ dgf,
    const unsigned long long* __restrict__ scP,
    float* __restrict__ sN, float* __restrict__ cN, float* __restrict__ mom)
{
    int t = threadIdx.x, b = blockIdx.x;
    int i = b * 256 + t;
    float a0 = 0.f, a1 = 0.f, a2 = 0.f, a3 = 0.f, a4 = 0.f;
    if (i < N_NODES) {
        start[i] += boff[b];
        dgf[i] = (float)degc[i];
        unsigned long long v = scP[i];
        unsigned cnt = (unsigned)(v & 0xFFFFFULL);
        long long sp = (long long)(v >> 20) - ((long long)cnt << 30);
        float s = (float)sp * (1.0f / 65536.0f);
        float c = (float)cnt;
        sN[i] = s; cN[i] = c;
        a0 = s; a1 = s * s; a2 = c; a3 = c * c; a4 = s * c;
    }
    if (i == 0) start[N_NODES] = N_EDGES;
    #pragma unroll
    for (int off = 32; off > 0; off >>= 1) {
        a0 += __shfl_down(a0, off);
        a1 += __shfl_down(a1, off);
        a2 += __shfl_down(a2, off);
        a3 += __shfl_down(a3, off);
        a4 += __shfl_down(a4, off);
    }
    if ((t & 63) == 0) {
        atomicAdd(&mom[0], a0);
        atomicAdd(&mom[1], a1);
        atomicAdd(&mom[2], a2);
        atomicAdd(&mom[3], a3);
        atomicAdd(&mom[4], a4);
    }
}

__global__ __launch_bounds__(256) void bucket_kernel(
    const int* __restrict__ ei, const int* __restrict__ start,
    int* __restrict__ cursor, int* __restrict__ csr)
{
    int e = blockIdx.x * 256 + threadIdx.x;   // grid = 2500*256 == N_EDGES
    int r = ei[e];
    int d = ei[N_EDGES + e];
    int pos = atomicAdd(&cursor[d], 1);
    csr[start[d] + pos] = r;
}

// ---------------------------------------------------------------------------
// Gather with inline bn+relu: G[d] = sum over in-edges of relu(a*P[src]+b)
// ---------------------------------------------------------------------------
__global__ __launch_bounds__(256) void gather_bn_kernel(
    const int* __restrict__ start, const int* __restrict__ csr,
    const float* __restrict__ P,
    const float* __restrict__ stats_in, const float* __restrict__ g_in,
    const float* __restrict__ bt_in,
    float* __restrict__ G)
{
    __shared__ float aT[128], bT[128];
    int t = threadIdx.x;
    if (t < 128) {
        float m = stats_in[t] * RCP_N;
        float v = stats_in[128 + t] * RCP_N - m * m;
        float a = g_in[t] * rsqrtf(v + BN_EPS);
        aT[t] = a; bT[t] = bt_in[t] - m * a;
    }
    __syncthreads();
    int wid = (blockIdx.x * 256 + t) >> 6;
    int lane = t & 63;
    if (wid >= N_NODES) return;
    float a0 = aT[2 * lane], b0 = bT[2 * lane];
    float a1 = aT[2 * lane + 1], b1 = bT[2 * lane + 1];
    int e0 = start[wid], e1 = start[wid + 1];
    float s0 = 0.f, s1 = 0.f, s2 = 0.f, s3 = 0.f;
    int e = e0;
    for (; e + 1 < e1; e += 2) {
        int r0 = csr[e], r1 = csr[e + 1];
        float2 v0 = *(const float2*)&P[(size_t)r0 * 128 + 2 * lane];
        float2 v1 = *(const float2*)&P[(size_t)r1 * 128 + 2 * lane];
        s0 += fmaxf(0.f, fmaf(v0.x, a0, b0));
        s1 += fmaxf(0.f, fmaf(v0.y, a1, b1));
        s2 += fmaxf(0.f, fmaf(v1.x, a0, b0));
        s3 += fmaxf(0.f, fmaf(v1.y, a1, b1));
    }
    if (e < e1) {
        float2 v0 = *(const float2*)&P[(size_t)csr[e] * 128 + 2 * lane];
        s0 += fmaxf(0.f, fmaf(v0.x, a0, b0));
        s1 += fmaxf(0.f, fmaf(v0.y, a1, b1));
    }
    float2 o = {s0 + s2, s1 + s3};
    *(float2*)&G[(size_t)wid * 128 + 2 * lane] = o;
}

// ---------------------------------------------------------------------------
// Initial node MLP pre-activation: Z = node_attr @ W0 + b0 (K=2), + col stats
// ---------------------------------------------------------------------------
__global__ __launch_bounds__(256) void init_node_kernel(
    const float* __restrict__ na, const float* __restrict__ W0,
    const float* __restrict__ b0, float* __restrict__ Z, float* __restrict__ st)
{
    int t = threadIdx.x;
    int col = t & 127, rh = t >> 7;
    float w0 = W0[col], w1 = W0[128 + col], bb = b0[col];
    int rbase = blockIdx.x * 64;
    float sm = 0.f, sq = 0.f;
    #pragma unroll 4
    for (int i = 0; i < 32; ++i) {
        int r = rbase + rh + i * 2;
        float2 nv = *(const float2*)&na[r * 2];
        float v = fmaf(nv.x, w0, fmaf(nv.y, w1, bb));
        Z[(size_t)r * 128 + col] = v;
        sm += v; sq += v * v;
    }
    __shared__ float red[256];
    red[t] = sm; __syncthreads();
    if (t < 128) atomicAdd(&st[t], red[t] + red[t + 128]);
    __syncthreads();
    red[t] = sq; __syncthreads();
    if (t < 128) atomicAdd(&st[128 + t], red[t] + red[t + 128]);
}

// ---------------------------------------------------------------------------
// Weight prep: Wt[mat][n][k] = f16(W[mat][k][n]), 12 matrices of 128x128.
// ---------------------------------------------------------------------------
__global__ __launch_bounds__(256) void wprep_kernel(
    const float* __restrict__ Wnode, const float* __restrict__ Wnb,
    const float* __restrict__ Wm1, const float* __restrict__ Wm2,
    unsigned short* __restrict__ Wt)
{
    __shared__ float tile[32][129];
    int b = blockIdx.x;
    int mat = b >> 2, kc = (b & 3) * 32;
    int grp = mat / 3, lay = mat % 3;
    const float* src = (grp == 0) ? Wnode : (grp == 1) ? Wnb : (grp == 2) ? Wm1 : Wm2;
    src += (size_t)lay * 16384;
    int t = threadIdx.x;
    #pragma unroll
    for (int i = 0; i < 16; ++i) {
        int idx = t + i * 256;
        int r = idx >> 7, n = idx & 127;
        tile[r][n] = src[(size_t)(kc + r) * 128 + n];
    }
    __syncthreads();
    int n = t >> 1, h = (t & 1) * 16;
    ushort8v o0, o1;
    #pragma unroll
    for (int j = 0; j < 8; ++j) o0[j] = f2h(tile[h + j][n]);
    #pragma unroll
    for (int j = 0; j < 8; ++j) o1[j] = f2h(tile[h + 8 + j][n]);
    unsigned short* dst = &Wt[(size_t)mat * 16384 + n * 128 + kc + h];
    *(ushort8v*)dst = o0;
    *(ushort8v*)(dst + 8) = o1;
}

// ---------------------------------------------------------------------------
// MFMA GEMM (f16 operands, f32 accum): Out = T(A...) @ W + bias, + col stats.
//   AMODE 0: A f32 plain
//   AMODE 1: A f32 with relu(a*x+b) from (st1, g1, bt1)
//   AMODE 2: fused combine: relu(bn(A) + bn(A2) + analytic edge bn)
//   RSC: bias scaled per-row by rowscale[r]
// ---------------------------------------------------------------------------
template<int AMODE, bool RSC>
__global__ __launch_bounds__(256) void mfma_gemm_kernel(
    const float* __restrict__ A, const float* __restrict__ A2,
    const unsigned short* __restrict__ Wt,
    const float* __restrict__ bias, const float* __restrict__ rowscale,
    const float* __restrict__ st1, const float* __restrict__ g1, const float* __restrict__ bt1,
    const float* __restrict__ st2, const float* __restrict__ g2, const float* __restrict__ bt2,
    const float* __restrict__ sN, const float* __restrict__ cN,
    const float* __restrict__ scal,
    const float* __restrict__ We, const float* __restrict__ Be,
    const float* __restrict__ ge, const float* __restrict__ bte,
    float* __restrict__ Out, float* __restrict__ stats_out)
{
    __shared__ __align__(16) unsigned short As[64 * 128];   // swizzled f16
    __shared__ __align__(16) unsigned short Bs[128 * 128];  // swizzled f16 W^T
    __shared__ float C1[128], D1[128], C2[128], D2[128];
    __shared__ float AE[128], BE[128], CE[128];
    __shared__ float redS[4][128], redQ[4][128];

    const int t = threadIdx.x;
    const int row0 = blockIdx.x * 64;

    if (AMODE == 1) {
        if (t < 128) {
            float m = st1[t] * RCP_N;
            float v = st1[128 + t] * RCP_N - m * m;
            float a = g1[t] * rsqrtf(v + BN_EPS);
            C1[t] = a; D1[t] = bt1[t] - m * a;
        }
        __syncthreads();
    } else if (AMODE == 2) {
        if (t < 128) {
            float m = st1[t] * RCP_N;
            float v = st1[128 + t] * RCP_N - m * m;
            float a = g1[t] * rsqrtf(v + BN_EPS);
            C1[t] = a; D1[t] = bt1[t] - m * a;

            m = st2[t] * RCP_N;
            v = st2[128 + t] * RCP_N - m * m;
            a = g2[t] * rsqrtf(v + BN_EPS);
            C2[t] = a; D2[t] = bt2[t] - m * a;

            float ms = scal[0] * RCP_N, vs = scal[1] * RCP_N - ms * ms;
            float mc = scal[2] * RCP_N, vc = scal[3] * RCP_N - mc * mc;
            float cov = scal[4] * RCP_N - ms * mc;
            float we = We[t], be = Be[t];
            float me = ms * we + mc * be;
            float ve = we * we * vs + be * be * vc + 2.f * we * be * cov;
            a = ge[t] * rsqrtf(ve + BN_EPS);
            AE[t] = we * a; BE[t] = be * a; CE[t] = bte[t] - me * a;
        }
        __syncthreads();
    }

    // ---- stage B (W^T f16, 128x128) with XOR swizzle
    #pragma unroll
    for (int i = 0; i < 8; ++i) {
        int cch = t + i * 256;
        int n = cch >> 4, off = (cch & 15) << 3;
        ushort8v w = *(const ushort8v*)&Wt[n * 128 + off];
        *(ushort8v*)&Bs[(n * 128 + off) ^ ((n & 7) << 3)] = w;
    }
    // ---- stage A (64x128 f32 -> transformed f16) with XOR swizzle
    #pragma unroll
    for (int i = 0; i < 4; ++i) {
        int cch = t + i * 256;
        int r = cch >> 4, off = (cch & 15) << 3;
        const float* Ar = &A[(size_t)(row0 + r) * 128 + off];
        float4 f0 = *(const float4*)Ar;
        float4 f1 = *(const float4*)(Ar + 4);
        float fv[8] = {f0.x, f0.y, f0.z, f0.w, f1.x, f1.y, f1.z, f1.w};
        ushort8v o;
        if (AMODE == 2) {
            const float* Gr = &A2[(size_t)(row0 + r) * 128 + off];
            float4 g0v = *(const float4*)Gr;
            float4 g1v = *(const float4*)(Gr + 4);
            float gv[8] = {g0v.x, g0v.y, g0v.z, g0v.w, g1v.x, g1v.y, g1v.z, g1v.w};
            float sr = sN[row0 + r], cr = cN[row0 + r];
            #pragma unroll
            for (int j = 0; j < 8; ++j) {
                int q = off + j;
                float y = fv[j] * C1[q] + D1[q] + gv[j] * C2[q] + D2[q]
                        + sr * AE[q] + cr * BE[q] + CE[q];
                o[j] = f2h(fmaxf(0.f, y));
            }
        } else {
            #pragma unroll
            for (int j = 0; j < 8; ++j) {
                float v = fv[j];
                if (AMODE == 1) v = fmaxf(0.f, fmaf(v, C1[off + j], D1[off + j]));
                o[j] = f2h(v);
            }
        }
        *(ushort8v*)&As[(r * 128 + off) ^ ((r & 7) << 3)] = o;
    }
    __syncthreads();

    const int w = t >> 6, lane = t & 63;
    const int la = lane & 15, lb = lane >> 4;

    const int ar = (w << 4) + la;
    const int abase = ar * 128 + lb * 8;
    const int aswz = (ar & 7) << 3;
    f16x8v afrag[4];
    #pragma unroll
    for (int s = 0; s < 4; ++s)
        afrag[s] = *(const f16x8v*)&As[(abase + (s << 5)) ^ aswz];

    f32x4v acc[8];
    #pragma unroll
    for (int c = 0; c < 8; ++c) acc[c] = (f32x4v){0.f, 0.f, 0.f, 0.f};

    #pragma unroll
    for (int c = 0; c < 8; ++c) {
        int bn_ = (c << 4) + la;
        int bbase = bn_ * 128 + lb * 8;
        int bswz = (bn_ & 7) << 3;
        #pragma unroll
        for (int s = 0; s < 4; ++s) {
            f16x8v bfrag = *(const f16x8v*)&Bs[(bbase + (s << 5)) ^ bswz];
            acc[c] = __builtin_amdgcn_mfma_f32_16x16x32_f16(afrag[s], bfrag, acc[c], 0, 0, 0);
        }
    }

    // ---- epilogue: bias, write, column stats
    const int orow0 = row0 + (w << 4) + lb * 4;
    float rsj[4];
    if (RSC) {
        #pragma unroll
        for (int j = 0; j < 4; ++j) rsj[j] = rowscale[orow0 + j];
    }
    float csum[8], csq[8];
    #pragma unroll
    for (int c = 0; c < 8; ++c) {
        int col = (c << 4) + la;
        float bc = bias[col];
        float s0 = 0.f, s1 = 0.f;
        #pragma unroll
        for (int j = 0; j < 4; ++j) {
            float v = acc[c][j] + (RSC ? rsj[j] * bc : bc);
            Out[(size_t)(orow0 + j) * 128 + col] = v;
            s0 += v; s1 += v * v;
        }
        csum[c] = s0; csq[c] = s1;
    }
    #pragma unroll
    for (int c = 0; c < 8; ++c) {
        csum[c] += __shfl_xor(csum[c], 16);
        csum[c] += __shfl_xor(csum[c], 32);
        csq[c]  += __shfl_xor(csq[c], 16);
        csq[c]  += __shfl_xor(csq[c], 32);
    }
    if (lane < 16) {
        #pragma unroll
        for (int c = 0; c < 8; ++c) {
            redS[w][(c << 4) + lane] = csum[c];
            redQ[w][(c << 4) + lane] = csq[c];
        }
    }
    __syncthreads();
    if (t < 128) {
        atomicAdd(&stats_out[t], redS[0][t] + redS[1][t] + redS[2][t] + redS[3][t]);
        atomicAdd(&stats_out[128 + t], redQ[0][t] + redQ[1][t] + redQ[2][t] + redQ[3][t]);
    }
}

// Final elementwise: out = relu(bn(Z)) f32
__global__ __launch_bounds__(256) void bnrelu_kernel(
    const float* __restrict__ Z, const float* __restrict__ stz,
    const float* __restrict__ g, const float* __restrict__ bt,
    float* __restrict__ O)
{
    __shared__ float aT[128], bT[128];
    int t = threadIdx.x;
    if (t < 128) {
        float m = stz[t] * RCP_N;
        float v = stz[128 + t] * RCP_N - m * m;
        float a = g[t] * rsqrtf(v + BN_EPS);
        aT[t] = a; bT[t] = bt[t] - m * a;
    }
    __syncthreads();
    int stride = gridDim.x * 256;
    for (int idx = blockIdx.x * 256 + t; idx < N_NODES * 32; idx += stride) {
        int r = idx >> 5;
        int q = (idx & 31) * 4;
        float4 z = *(const float4*)&Z[(size_t)r * 128 + q];
        float4 o;
        o.x = fmaxf(0.f, fmaf(z.x, aT[q],     bT[q]));
        o.y = fmaxf(0.f, fmaf(z.y, aT[q + 1], bT[q + 1]));
        o.z = fmaxf(0.f, fmaf(z.z, aT[q + 2], bT[q + 2]));
        o.w = fmaxf(0.f, fmaf(z.w, aT[q + 3], bT[q + 3]));
        *(float4*)&O[(size_t)r * 128 + q] = o;
    }
}

// ---------------------------------------------------------------------------
extern "C" void kernel_launch(void* const* d_in, const int* in_sizes, int n_in,
                              void* d_out, int out_size, void* d_ws, size_t ws_size,
                              hipStream_t stream)
{
    const float* node_attr = (const float*)d_in[0];
    const int*   ei        = (const int*)d_in[1];
    const float* ea        = (const float*)d_in[2];
    const float* W0    = (const float*)d_in[3];
    const float* b0    = (const float*)d_in[4];
    const float* g0    = (const float*)d_in[5];
    const float* bt0   = (const float*)d_in[6];
    const float* Wnode = (const float*)d_in[7];
    const float* bnode = (const float*)d_in[8];
    const float* Wedge = (const float*)d_in[9];
    const float* bedge = (const float*)d_in[10];
    const float* Wnb   = (const float*)d_in[11];
    const float* bnb   = (const float*)d_in[12];
    const float* gn    = (const float*)d_in[13];
    const float* ge    = (const float*)d_in[14];
    const float* gnb   = (const float*)d_in[15];
    const float* gm1   = (const float*)d_in[16];
    const float* gm2   = (const float*)d_in[17];
    const float* btn   = (const float*)d_in[18];
    const float* bte   = (const float*)d_in[19];
    const float* btnb  = (const float*)d_in[20];
    const float* btm1  = (const float*)d_in[21];
    const float* btm2  = (const float*)d_in[22];
    const float* Wm1   = (const float*)d_in[23];
    const float* bm1   = (const float*)d_in[24];
    const float* Wm2   = (const float*)d_in[25];
    const float* bm2   = (const float*)d_in[26];
    float* out = (float*)d_out;

    // workspace (floats):
    // P(NF) | ZN(NF) | G(NF) | sN | cN | dg | st(4096) | scP(u64,N)
    // | degc(u32,N) | cursor(N) | startA(N+64) | scanTmp(512) | csr(E) | Wtb
    float* ws = (float*)d_ws;
    float* P  = ws;
    float* ZN = ws + NF;
    float* G  = ws + 2 * NF;
    float* sN = ws + 3 * NF;
    float* cN = sN + N_NODES;
    float* dg = cN + N_NODES;
    float* st = dg + N_NODES;
    unsigned long long* scP = (unsigned long long*)(st + 4096);
    unsigned* degc = (unsigned*)(scP + N_NODES);
    int* cursor = (int*)(degc + N_NODES);
    int* startA = cursor + N_NODES;
    int* bsum   = startA + N_NODES + 64;
    int* boff   = bsum + 256;
    int* csr    = boff + 256;
    unsigned short* Wtb = (unsigned short*)(csr + N_EDGES);
    // stats: st[0..255] init | st[256..260] scalar moments | layer i at
    //   264+i*1024: zn(+0), aggr(+256), z1(+512), z2(+768)

    // zero st | scP | degc | cursor (contiguous)
    hipMemsetAsync(st, 0, (size_t)(4096 + 2 * N_NODES + 2 * N_NODES) * sizeof(float), stream);
    wprep_kernel<<<48, 256, 0, stream>>>(Wnode, Wnb, Wm1, Wm2, Wtb);
    edge_pack_kernel<<<2500, 256, 0, stream>>>(ei, ea, scP, degc);
    scan1_kernel<<<NB_SCAN, 256, 0, stream>>>(degc, startA, bsum);
    scan2_kernel<<<1, 256, 0, stream>>>(bsum, boff);
    scan3_decode_kernel<<<NB_SCAN, 256, 0, stream>>>(
        degc, boff, startA, dg, scP, sN, cN, st + 256);
    bucket_kernel<<<2500, 256, 0, stream>>>(ei, startA, cursor, csr);
    init_node_kernel<<<625, 256, 0, stream>>>(node_attr, W0, b0, P, st);

    const float* xst = st;
    const float* xg  = g0;
    const float* xbt = bt0;

    for (int i = 0; i < 3; ++i) {
        float* lay = st + 264 + i * 1024;
        // G = sum over in-edges of relu(bn(P[src]))
        gather_bn_kernel<<<10000, 256, 0, stream>>>(startA, csr, P, xst, xg, xbt, G);
        // node branch: ZN = relu(bn(P)) @ Wnode + bnode (+stats)
        mfma_gemm_kernel<1, false><<<625, 256, 0, stream>>>(
            P, nullptr, Wtb + (size_t)(0 + i) * 16384, bnode + i * 128, nullptr,
            xst, xg, xbt, nullptr, nullptr, nullptr,
            nullptr, nullptr, nullptr, nullptr, nullptr, nullptr, nullptr,
            ZN, lay);
        // neighbor branch: G = G @ Wnb + deg*bnb (+stats), in place
        mfma_gemm_kernel<0, true><<<625, 256, 0, stream>>>(
            G, nullptr, Wtb + (size_t)(3 + i) * 16384, bnb + i * 128, dg,
            nullptr, nullptr, nullptr, nullptr, nullptr, nullptr,
            nullptr, nullptr, nullptr, nullptr, nullptr, nullptr, nullptr,
            G, lay + 256);
        // z1 = relu(bn(ZN)+bn(G)+ea) @ Wm1 + bm1 (+stats) -> ZN (fused combine)
        mfma_gemm_kernel<2, false><<<625, 256, 0, stream>>>(
            ZN, G, Wtb + (size_t)(6 + i) * 16384, bm1 + i * 128, nullptr,
            lay, gn + i * 128, btn + i * 128,
            lay + 256, gnb + i * 128, btnb + i * 128,
            sN, cN, st + 256,
            Wedge + i * 128, bedge + i * 128, ge + i * 128, bte + i * 128,
            ZN, lay + 512);
        // z2 = relu(bn(z1)) @ Wm2 + bm2 (+stats) -> P
        mfma_gemm_kernel<1, false><<<625, 256, 0, stream>>>(
            ZN, nullptr, Wtb + (size_t)(9 + i) * 16384, bm2 + i * 128, nullptr,
            lay + 512, gm1 + i * 128, btm1 + i * 128, nullptr, nullptr, nullptr,
            nullptr, nullptr, nullptr, nullptr, nullptr, nullptr, nullptr,
            P, lay + 768);

        xst = lay + 768;
        xg  = gm2 + i * 128;
        xbt = btm2 + i * 128;
    }
    bnrelu_kernel<<<2048, 256, 0, stream>>>(P, xst, xg, xbt, out);
}

// Round 6
// 610.033 us; speedup vs baseline: 3.7259x; 1.1112x over previous
//
#include <hip/hip_runtime.h>

#define N_NODES 40000
#define N_EDGES 640000
#define EMB 128
#define NF ((size_t)N_NODES * EMB)
#define RCP_N (1.0f / (float)N_NODES)
#define BN_EPS 1e-5f
#define CAP 64          // fixed bucket capacity (avg deg 16; P(>64) ~ 1e-18)

typedef _Float16 f16x8v __attribute__((ext_vector_type(8)));
typedef float f32x4v __attribute__((ext_vector_type(4)));
typedef unsigned short ushort8v __attribute__((ext_vector_type(8)));

__device__ __forceinline__ unsigned short f2h(float v) {
    return __builtin_bit_cast(unsigned short, (_Float16)v);
}
__device__ __forceinline__ float h2f(unsigned short u) {
    return (float)__builtin_bit_cast(_Float16, u);
}
__device__ __forceinline__ float h2f_lo(unsigned u) {
    return (float)__builtin_bit_cast(_Float16, (unsigned short)(u & 0xffffu));
}
__device__ __forceinline__ float h2f_hi(unsigned u) {
    return (float)__builtin_bit_cast(_Float16, (unsigned short)(u >> 16));
}

// ---------------------------------------------------------------------------
// Single per-edge pass:
//  - scP[row] += pack(ea,1)   (u64: s & c moments by source)
//  - pos = cursor[col]++ ; slot[col*CAP + pos] = row   (bucketed in-neighbors)
// ---------------------------------------------------------------------------
__global__ __launch_bounds__(256) void edge_slot_kernel(
    const int* __restrict__ ei, const float* __restrict__ ea,
    unsigned long long* __restrict__ scP, unsigned* __restrict__ cursor,
    int* __restrict__ slot)
{
    int e = blockIdx.x * 256 + threadIdx.x;   // grid = 2500*256 == N_EDGES
    int r = ei[e];
    int d = ei[N_EDGES + e];
    int fx = (int)rintf(ea[e] * 65536.0f);
    unsigned long long add =
        (((unsigned long long)(unsigned)(fx + 0x40000000)) << 20) | 1ULL;
    atomicAdd(&scP[r], add);
    unsigned pos = atomicAdd(&cursor[d], 1u);
    slot[(size_t)d * CAP + (pos < CAP ? pos : CAP - 1)] = r;
}

// Decode scP -> sN, cN + scalar moments; cursor -> f32 deg.  grid 157
__global__ __launch_bounds__(256) void decode_kernel(
    const unsigned long long* __restrict__ scP, const unsigned* __restrict__ cursor,
    float* __restrict__ sN, float* __restrict__ cN, float* __restrict__ dgf,
    float* __restrict__ mom)
{
    int t = threadIdx.x;
    int i = blockIdx.x * 256 + t;
    float a0 = 0.f, a1 = 0.f, a2 = 0.f, a3 = 0.f, a4 = 0.f;
    if (i < N_NODES) {
        unsigned long long v = scP[i];
        unsigned cnt = (unsigned)(v & 0xFFFFFULL);
        long long sp = (long long)(v >> 20) - ((long long)cnt << 30);
        float s = (float)sp * (1.0f / 65536.0f);
        float c = (float)cnt;
        sN[i] = s; cN[i] = c;
        dgf[i] = (float)cursor[i];
        a0 = s; a1 = s * s; a2 = c; a3 = c * c; a4 = s * c;
    }
    #pragma unroll
    for (int off = 32; off > 0; off >>= 1) {
        a0 += __shfl_down(a0, off);
        a1 += __shfl_down(a1, off);
        a2 += __shfl_down(a2, off);
        a3 += __shfl_down(a3, off);
        a4 += __shfl_down(a4, off);
    }
    if ((t & 63) == 0) {
        atomicAdd(&mom[0], a0);
        atomicAdd(&mom[1], a1);
        atomicAdd(&mom[2], a2);
        atomicAdd(&mom[3], a3);
        atomicAdd(&mom[4], a4);
    }
}

// ---------------------------------------------------------------------------
// Gather with inline bn+relu: G[d] = sum_{j<cnt[d]} relu(a*P[slot[d][j]]+b)
// One wave per node; P,G are f16; accumulation f32.
// ---------------------------------------------------------------------------
__global__ __launch_bounds__(256) void gather_bn_kernel(
    const unsigned* __restrict__ cnt, const int* __restrict__ slot,
    const unsigned short* __restrict__ Ph,
    const float* __restrict__ stats_in, const float* __restrict__ g_in,
    const float* __restrict__ bt_in,
    unsigned short* __restrict__ Gh)
{
    __shared__ float aT[128], bT[128];
    int t = threadIdx.x;
    if (t < 128) {
        float m = stats_in[t] * RCP_N;
        float v = stats_in[128 + t] * RCP_N - m * m;
        float a = g_in[t] * rsqrtf(v + BN_EPS);
        aT[t] = a; bT[t] = bt_in[t] - m * a;
    }
    __syncthreads();
    int wid = (blockIdx.x * 256 + t) >> 6;   // grid 10000 -> 40000 waves
    int lane = t & 63;
    float a0 = aT[2 * lane], b0 = bT[2 * lane];
    float a1 = aT[2 * lane + 1], b1 = bT[2 * lane + 1];
    int n = (int)cnt[wid];
    const int* sl = &slot[(size_t)wid * CAP];
    float s0 = 0.f, s1 = 0.f, s2 = 0.f, s3 = 0.f;
    int j = 0;
    for (; j + 1 < n; j += 2) {
        int r0 = sl[j], r1 = sl[j + 1];
        unsigned v0 = *(const unsigned*)&Ph[(size_t)r0 * 128 + 2 * lane];
        unsigned v1 = *(const unsigned*)&Ph[(size_t)r1 * 128 + 2 * lane];
        s0 += fmaxf(0.f, fmaf(h2f_lo(v0), a0, b0));
        s1 += fmaxf(0.f, fmaf(h2f_hi(v0), a1, b1));
        s2 += fmaxf(0.f, fmaf(h2f_lo(v1), a0, b0));
        s3 += fmaxf(0.f, fmaf(h2f_hi(v1), a1, b1));
    }
    if (j < n) {
        unsigned v0 = *(const unsigned*)&Ph[(size_t)sl[j] * 128 + 2 * lane];
        s0 += fmaxf(0.f, fmaf(h2f_lo(v0), a0, b0));
        s1 += fmaxf(0.f, fmaf(h2f_hi(v0), a1, b1));
    }
    unsigned o = (unsigned)f2h(s0 + s2) | ((unsigned)f2h(s1 + s3) << 16);
    *(unsigned*)&Gh[(size_t)wid * 128 + 2 * lane] = o;
}

// ---------------------------------------------------------------------------
// Initial node MLP: P(f16) = node_attr @ W0 + b0 (K=2), + f32 col stats
// ---------------------------------------------------------------------------
__global__ __launch_bounds__(256) void init_node_kernel(
    const float* __restrict__ na, const float* __restrict__ W0,
    const float* __restrict__ b0, unsigned short* __restrict__ Z,
    float* __restrict__ st)
{
    int t = threadIdx.x;
    int col = t & 127, rh = t >> 7;
    float w0 = W0[col], w1 = W0[128 + col], bb = b0[col];
    int rbase = blockIdx.x * 64;
    float sm = 0.f, sq = 0.f;
    #pragma unroll 4
    for (int i = 0; i < 32; ++i) {
        int r = rbase + rh + i * 2;
        float2 nv = *(const float2*)&na[r * 2];
        float v = fmaf(nv.x, w0, fmaf(nv.y, w1, bb));
        Z[(size_t)r * 128 + col] = f2h(v);
        sm += v; sq += v * v;
    }
    __shared__ float red[256];
    red[t] = sm; __syncthreads();
    if (t < 128) atomicAdd(&st[t], red[t] + red[t + 128]);
    __syncthreads();
    red[t] = sq; __syncthreads();
    if (t < 128) atomicAdd(&st[128 + t], red[t] + red[t + 128]);
}

// ---------------------------------------------------------------------------
// Weight prep: Wt[mat][n][k] = f16(W[mat][k][n]), 12 matrices of 128x128.
// ---------------------------------------------------------------------------
__global__ __launch_bounds__(256) void wprep_kernel(
    const float* __restrict__ Wnode, const float* __restrict__ Wnb,
    const float* __restrict__ Wm1, const float* __restrict__ Wm2,
    unsigned short* __restrict__ Wt)
{
    __shared__ float tile[32][129];
    int b = blockIdx.x;
    int mat = b >> 2, kc = (b & 3) * 32;
    int grp = mat / 3, lay = mat % 3;
    const float* src = (grp == 0) ? Wnode : (grp == 1) ? Wnb : (grp == 2) ? Wm1 : Wm2;
    src += (size_t)lay * 16384;
    int t = threadIdx.x;
    #pragma unroll
    for (int i = 0; i < 16; ++i) {
        int idx = t + i * 256;
        int r = idx >> 7, n = idx & 127;
        tile[r][n] = src[(size_t)(kc + r) * 128 + n];
    }
    __syncthreads();
    int n = t >> 1, h = (t & 1) * 16;
    ushort8v o0, o1;
    #pragma unroll
    for (int j = 0; j < 8; ++j) o0[j] = f2h(tile[h + j][n]);
    #pragma unroll
    for (int j = 0; j < 8; ++j) o1[j] = f2h(tile[h + 8 + j][n]);
    unsigned short* dst = &Wt[(size_t)mat * 16384 + n * 128 + kc + h];
    *(ushort8v*)dst = o0;
    *(ushort8v*)(dst + 8) = o1;
}

// ---------------------------------------------------------------------------
// MFMA GEMM (f16 in/out, f32 accum): Out = T(A...) @ W + bias, + col stats.
//   AMODE 0: A plain f16 copy
//   AMODE 1: relu(a*x+b) on A
//   AMODE 2: fused combine: relu(bn(A) + bn(A2) + analytic edge bn)
//   RSC: bias scaled per-row by rowscale[r]
// ---------------------------------------------------------------------------
template<int AMODE, bool RSC>
__global__ __launch_bounds__(256) void mfma_gemm_kernel(
    const unsigned short* __restrict__ A, const unsigned short* __restrict__ A2,
    const unsigned short* __restrict__ Wt,
    const float* __restrict__ bias, const float* __restrict__ rowscale,
    const float* __restrict__ st1, const float* __restrict__ g1, const float* __restrict__ bt1,
    const float* __restrict__ st2, const float* __restrict__ g2, const float* __restrict__ bt2,
    const float* __restrict__ sN, const float* __restrict__ cN,
    const float* __restrict__ scal,
    const float* __restrict__ We, const float* __restrict__ Be,
    const float* __restrict__ ge, const float* __restrict__ bte,
    unsigned short* __restrict__ Out, float* __restrict__ stats_out)
{
    __shared__ __align__(16) unsigned short As[64 * 128];   // swizzled f16
    __shared__ __align__(16) unsigned short Bs[128 * 128];  // swizzled f16 W^T
    __shared__ float C1[128], D1[128], C2[128], D2[128];
    __shared__ float AE[128], BE[128], CE[128];
    __shared__ float redS[4][128], redQ[4][128];

    const int t = threadIdx.x;
    const int row0 = blockIdx.x * 64;

    if (AMODE == 1) {
        if (t < 128) {
            float m = st1[t] * RCP_N;
            float v = st1[128 + t] * RCP_N - m * m;
            float a = g1[t] * rsqrtf(v + BN_EPS);
            C1[t] = a; D1[t] = bt1[t] - m * a;
        }
        __syncthreads();
    } else if (AMODE == 2) {
        if (t < 128) {
            float m = st1[t] * RCP_N;
            float v = st1[128 + t] * RCP_N - m * m;
            float a = g1[t] * rsqrtf(v + BN_EPS);
            C1[t] = a; D1[t] = bt1[t] - m * a;

            m = st2[t] * RCP_N;
            v = st2[128 + t] * RCP_N - m * m;
            a = g2[t] * rsqrtf(v + BN_EPS);
            C2[t] = a; D2[t] = bt2[t] - m * a;

            float ms = scal[0] * RCP_N, vs = scal[1] * RCP_N - ms * ms;
            float mc = scal[2] * RCP_N, vc = scal[3] * RCP_N - mc * mc;
            float cov = scal[4] * RCP_N - ms * mc;
            float we = We[t], be = Be[t];
            float me = ms * we + mc * be;
            float ve = we * we * vs + be * be * vc + 2.f * we * be * cov;
            a = ge[t] * rsqrtf(ve + BN_EPS);
            AE[t] = we * a; BE[t] = be * a; CE[t] = bte[t] - me * a;
        }
        __syncthreads();
    }

    // ---- stage B (W^T f16, 128x128) with XOR swizzle
    #pragma unroll
    for (int i = 0; i < 8; ++i) {
        int cch = t + i * 256;
        int n = cch >> 4, off = (cch & 15) << 3;
        ushort8v w = *(const ushort8v*)&Wt[n * 128 + off];
        *(ushort8v*)&Bs[(n * 128 + off) ^ ((n & 7) << 3)] = w;
    }
    // ---- stage A (64x128 f16 -> transformed f16) with XOR swizzle
    #pragma unroll
    for (int i = 0; i < 4; ++i) {
        int cch = t + i * 256;
        int r = cch >> 4, off = (cch & 15) << 3;
        ushort8v av = *(const ushort8v*)&A[(size_t)(row0 + r) * 128 + off];
        ushort8v o;
        if (AMODE == 0) {
            o = av;
        } else if (AMODE == 1) {
            #pragma unroll
            for (int j = 0; j < 8; ++j) {
                float v = fmaxf(0.f, fmaf(h2f(av[j]), C1[off + j], D1[off + j]));
                o[j] = f2h(v);
            }
        } else {
            ushort8v gv = *(const ushort8v*)&A2[(size_t)(row0 + r) * 128 + off];
            float sr = sN[row0 + r], cr = cN[row0 + r];
            #pragma unroll
            for (int j = 0; j < 8; ++j) {
                int q = off + j;
                float y = h2f(av[j]) * C1[q] + D1[q] + h2f(gv[j]) * C2[q] + D2[q]
                        + sr * AE[q] + cr * BE[q] + CE[q];
                o[j] = f2h(fmaxf(0.f, y));
            }
        }
        *(ushort8v*)&As[(r * 128 + off) ^ ((r & 7) << 3)] = o;
    }
    __syncthreads();

    const int w = t >> 6, lane = t & 63;
    const int la = lane & 15, lb = lane >> 4;

    const int ar = (w << 4) + la;
    const int abase = ar * 128 + lb * 8;
    const int aswz = (ar & 7) << 3;
    f16x8v afrag[4];
    #pragma unroll
    for (int s = 0; s < 4; ++s)
        afrag[s] = *(const f16x8v*)&As[(abase + (s << 5)) ^ aswz];

    f32x4v acc[8];
    #pragma unroll
    for (int c = 0; c < 8; ++c) acc[c] = (f32x4v){0.f, 0.f, 0.f, 0.f};

    #pragma unroll
    for (int c = 0; c < 8; ++c) {
        int bn_ = (c << 4) + la;
        int bbase = bn_ * 128 + lb * 8;
        int bswz = (bn_ & 7) << 3;
        #pragma unroll
        for (int s = 0; s < 4; ++s) {
            f16x8v bfrag = *(const f16x8v*)&Bs[(bbase + (s << 5)) ^ bswz];
            acc[c] = __builtin_amdgcn_mfma_f32_16x16x32_f16(afrag[s], bfrag, acc[c], 0, 0, 0);
        }
    }

    // ---- epilogue: bias, f16 write, f32 column stats
    const int orow0 = row0 + (w << 4) + lb * 4;
    float rsj[4];
    if (RSC) {
        #pragma unroll
        for (int j = 0; j < 4; ++j) rsj[j] = rowscale[orow0 + j];
    }
    float csum[8], csq[8];
    #pragma unroll
    for (int c = 0; c < 8; ++c) {
        int col = (c << 4) + la;
        float bc = bias[col];
        float s0 = 0.f, s1 = 0.f;
        #pragma unroll
        for (int j = 0; j < 4; ++j) {
            float v = acc[c][j] + (RSC ? rsj[j] * bc : bc);
            Out[(size_t)(orow0 + j) * 128 + col] = f2h(v);
            s0 += v; s1 += v * v;
        }
        csum[c] = s0; csq[c] = s1;
    }
    #pragma unroll
    for (int c = 0; c < 8; ++c) {
        csum[c] += __shfl_xor(csum[c], 16);
        csum[c] += __shfl_xor(csum[c], 32);
        csq[c]  += __shfl_xor(csq[c], 16);
        csq[c]  += __shfl_xor(csq[c], 32);
    }
    if (lane < 16) {
        #pragma unroll
        for (int c = 0; c < 8; ++c) {
            redS[w][(c << 4) + lane] = csum[c];
            redQ[w][(c << 4) + lane] = csq[c];
        }
    }
    __syncthreads();
    if (t < 128) {
        atomicAdd(&stats_out[t], redS[0][t] + redS[1][t] + redS[2][t] + redS[3][t]);
        atomicAdd(&stats_out[128 + t], redQ[0][t] + redQ[1][t] + redQ[2][t] + redQ[3][t]);
    }
}

// Final elementwise: out(f32) = relu(bn(Z f16))
__global__ __launch_bounds__(256) void bnrelu_kernel(
    const unsigned short* __restrict__ Z, const float* __restrict__ stz,
    const float* __restrict__ g, const float* __restrict__ bt,
    float* __restrict__ O)
{
    __shared__ float aT[128], bT[128];
    int t = threadIdx.x;
    if (t < 128) {
        float m = stz[t] * RCP_N;
        float v = stz[128 + t] * RCP_N - m * m;
        float a = g[t] * rsqrtf(v + BN_EPS);
        aT[t] = a; bT[t] = bt[t] - m * a;
    }
    __syncthreads();
    int stride = gridDim.x * 256;
    for (int idx = blockIdx.x * 256 + t; idx < N_NODES * 32; idx += stride) {
        int r = idx >> 5;
        int q = (idx & 31) * 4;
        ushort4 z = *(const ushort4*)&Z[(size_t)r * 128 + q];
        float4 o;
        o.x = fmaxf(0.f, fmaf(h2f(z.x), aT[q],     bT[q]));
        o.y = fmaxf(0.f, fmaf(h2f(z.y), aT[q + 1], bT[q + 1]));
        o.z = fmaxf(0.f, fmaf(h2f(z.z), aT[q + 2], bT[q + 2]));
        o.w = fmaxf(0.f, fmaf(h2f(z.w), aT[q + 3], bT[q + 3]));
        *(float4*)&O[(size_t)r * 128 + q] = o;
    }
}

// ---------------------------------------------------------------------------
extern "C" void kernel_launch(void* const* d_in, const int* in_sizes, int n_in,
                              void* d_out, int out_size, void* d_ws, size_t ws_size,
                              hipStream_t stream)
{
    const float* node_attr = (const float*)d_in[0];
    const int*   ei        = (const int*)d_in[1];
    const float* ea        = (const float*)d_in[2];
    const float* W0    = (const float*)d_in[3];
    const float* b0    = (const float*)d_in[4];
    const float* g0    = (const float*)d_in[5];
    const float* bt0   = (const float*)d_in[6];
    const float* Wnode = (const float*)d_in[7];
    const float* bnode = (const float*)d_in[8];
    const float* Wedge = (const float*)d_in[9];
    const float* bedge = (const float*)d_in[10];
    const float* Wnb   = (const float*)d_in[11];
    const float* bnb   = (const float*)d_in[12];
    const float* gn    = (const float*)d_in[13];
    const float* ge    = (const float*)d_in[14];
    const float* gnb   = (const float*)d_in[15];
    const float* gm1   = (const float*)d_in[16];
    const float* gm2   = (const float*)d_in[17];
    const float* btn   = (const float*)d_in[18];
    const float* bte   = (const float*)d_in[19];
    const float* btnb  = (const float*)d_in[20];
    const float* btm1  = (const float*)d_in[21];
    const float* btm2  = (const float*)d_in[22];
    const float* Wm1   = (const float*)d_in[23];
    const float* bm1   = (const float*)d_in[24];
    const float* Wm2   = (const float*)d_in[25];
    const float* bm2   = (const float*)d_in[26];
    float* out = (float*)d_out;

    // workspace: Ph|ZNh|Gh (f16, NF each) | sN|cN|dg (f32) | st(4096)
    //            | scP(u64,N) | cursor(u32,N) | slot(int, N*CAP) | Wtb(f16)
    unsigned short* Ph  = (unsigned short*)d_ws;
    unsigned short* ZNh = Ph + NF;
    unsigned short* Gh  = ZNh + NF;
    float* sN = (float*)(Gh + NF);
    float* cN = sN + N_NODES;
    float* dg = cN + N_NODES;
    float* st = dg + N_NODES;
    unsigned long long* scP = (unsigned long long*)(st + 4096);
    unsigned* cursor = (unsigned*)(scP + N_NODES);
    int* slot = (int*)(cursor + N_NODES);
    unsigned short* Wtb = (unsigned short*)(slot + (size_t)N_NODES * CAP);
    // stats: st[0..255] init | st[256..260] moments | layer i at 264+i*1024:
    //   zn(+0), aggr(+256), z1(+512), z2(+768)

    // zero st | scP | cursor (contiguous: 4096 + 2N + N floats)
    hipMemsetAsync(st, 0, (size_t)(4096 + 3 * N_NODES) * sizeof(float), stream);
    wprep_kernel<<<48, 256, 0, stream>>>(Wnode, Wnb, Wm1, Wm2, Wtb);
    edge_slot_kernel<<<2500, 256, 0, stream>>>(ei, ea, scP, cursor, slot);
    decode_kernel<<<157, 256, 0, stream>>>(scP, cursor, sN, cN, dg, st + 256);
    init_node_kernel<<<625, 256, 0, stream>>>(node_attr, W0, b0, Ph, st);

    const float* xst = st;
    const float* xg  = g0;
    const float* xbt = bt0;

    for (int i = 0; i < 3; ++i) {
        float* lay = st + 264 + i * 1024;
        // G = sum over in-neighbors of relu(bn(P[src]))
        gather_bn_kernel<<<10000, 256, 0, stream>>>(cursor, slot, Ph, xst, xg, xbt, Gh);
        // node branch: ZN = relu(bn(P)) @ Wnode + bnode (+stats)
        mfma_gemm_kernel<1, false><<<625, 256, 0, stream>>>(
            Ph, nullptr, Wtb + (size_t)(0 + i) * 16384, bnode + i * 128, nullptr,
            xst, xg, xbt, nullptr, nullptr, nullptr,
            nullptr, nullptr, nullptr, nullptr, nullptr, nullptr, nullptr,
            ZNh, lay);
        // neighbor branch: G = G @ Wnb + deg*bnb (+stats), in place
        mfma_gemm_kernel<0, true><<<625, 256, 0, stream>>>(
            Gh, nullptr, Wtb + (size_t)(3 + i) * 16384, bnb + i * 128, dg,
            nullptr, nullptr, nullptr, nullptr, nullptr, nullptr,
            nullptr, nullptr, nullptr, nullptr, nullptr, nullptr, nullptr,
            Gh, lay + 256);
        // z1 = relu(bn(ZN)+bn(G)+ea) @ Wm1 + bm1 (+stats) -> ZN (fused combine)
        mfma_gemm_kernel<2, false><<<625, 256, 0, stream>>>(
            ZNh, Gh, Wtb + (size_t)(6 + i) * 16384, bm1 + i * 128, nullptr,
            lay, gn + i * 128, btn + i * 128,
            lay + 256, gnb + i * 128, btnb + i * 128,
            sN, cN, st + 256,
            Wedge + i * 128, bedge + i * 128, ge + i * 128, bte + i * 128,
            ZNh, lay + 512);
        // z2 = relu(bn(z1)) @ Wm2 + bm2 (+stats) -> P
        mfma_gemm_kernel<1, false><<<625, 256, 0, stream>>>(
            ZNh, nullptr, Wtb + (size_t)(9 + i) * 16384, bm2 + i * 128, nullptr,
            lay + 512, gm1 + i * 128, btm1 + i * 128, nullptr, nullptr, nullptr,
            nullptr, nullptr, nullptr, nullptr, nullptr, nullptr, nullptr,
            Ph, lay + 768);

        xst = lay + 768;
        xg  = gm2 + i * 128;
        xbt = btm2 + i * 128;
    }
    bnrelu_kernel<<<2048, 256, 0, stream>>>(Ph, xst, xg, xbt, out);
}